// Round 5
// baseline (4208.268 us; speedup 1.0000x reference)
//
#include <hip/hip_runtime.h>
#include <hip/hip_bf16.h>
#include <math.h>

// Problem constants (from reference): N=100000 nodes, E=1600000 edges,
// D=128 in-feat, H=256 hidden, B=64 graphs. Output: [B,1] fp32.
// Round 4: identical to round 3 (never benched — infra timeouts); design held
// deliberately: blind changes add unvalidatable risk.
#define HDIM 256
#define NGRAPH 64
#define SCAN_CHUNK 2048  // 256 threads x 8 elems

// ---------------------------------------------------------------------------
// in-degree count (int atomics)
__global__ void deg_count_k(const int* __restrict__ dst, int* __restrict__ deg, int E, int n) {
    int i = blockIdx.x * blockDim.x + threadIdx.x;
    if (i < E) {
        int d = dst[i];
        if ((unsigned)d < (unsigned)n) atomicAdd(&deg[d], 1);
    }
}

// dinv[i] = 1/sqrt(in_deg[i] + 1)
__global__ void dinv_k(const int* __restrict__ deg, float* __restrict__ dinv, int n) {
    int i = blockIdx.x * blockDim.x + threadIdx.x;
    if (i < n) dinv[i] = 1.0f / sqrtf((float)deg[i] + 1.0f);
}

// last node index of each (sorted, consecutive) graph id
__global__ void last_idx_k(const int* __restrict__ batch, int* __restrict__ lastidx, int n) {
    int i = blockIdx.x * blockDim.x + threadIdx.x;
    if (i < n) {
        int b = batch[i];
        if ((i == n - 1 || batch[i + 1] != b) && b >= 0 && b < NGRAPH) lastidx[b] = i;
    }
}

// --------------------------- exclusive prefix scan -------------------------
// scan1: per-block (2048-elem chunk) sums
__global__ __launch_bounds__(256) void scan1_k(const int* __restrict__ deg,
                                               int* __restrict__ partial, int n) {
    __shared__ int sm[256];
    int t = threadIdx.x;
    int base = blockIdx.x * SCAN_CHUNK + t * 8;
    int s = 0;
#pragma unroll
    for (int j = 0; j < 8; j++) { int idx = base + j; if (idx < n) s += deg[idx]; }
    sm[t] = s; __syncthreads();
    for (int o = 128; o; o >>= 1) { if (t < o) sm[t] += sm[t + o]; __syncthreads(); }
    if (t == 0) partial[blockIdx.x] = sm[0];
}

// scan2: single block, exclusive scan of block partials (nb <= 1024); rs[n] = total
__global__ __launch_bounds__(1024) void scan2_k(int* __restrict__ partial, int nb,
                                                int* __restrict__ rs, int n) {
    __shared__ int sm[1024];
    int t = threadIdx.x;
    int v = (t < nb) ? partial[t] : 0;
    sm[t] = v; __syncthreads();
    for (int o = 1; o < 1024; o <<= 1) {
        int add = (t >= o) ? sm[t - o] : 0;
        __syncthreads();
        sm[t] += add;
        __syncthreads();
    }
    if (t < nb) partial[t] = sm[t] - v;  // exclusive block offset
    if (t == nb - 1) rs[n] = sm[t];      // total edge count
}

// scan3: write row_start (exclusive prefix) + cursor copy
__global__ __launch_bounds__(256) void scan3_k(const int* __restrict__ deg,
                                               const int* __restrict__ partial,
                                               int* __restrict__ rs, int* __restrict__ cur, int n) {
    __shared__ int sm[256];
    int t = threadIdx.x;
    int base = blockIdx.x * SCAN_CHUNK + t * 8;
    int loc[8]; int s = 0;
#pragma unroll
    for (int j = 0; j < 8; j++) {
        int idx = base + j;
        loc[j] = (idx < n) ? deg[idx] : 0;
        s += loc[j];
    }
    sm[t] = s; __syncthreads();
    int v = s;
    for (int o = 1; o < 256; o <<= 1) {
        int add = (t >= o) ? sm[t - o] : 0;
        __syncthreads();
        sm[t] += add;
        __syncthreads();
    }
    int run = partial[blockIdx.x] + sm[t] - v;  // exclusive prefix for this thread
#pragma unroll
    for (int j = 0; j < 8; j++) {
        int idx = base + j;
        if (idx < n) { rs[idx] = run; cur[idx] = run; }
        run += loc[j];
    }
}

// scatter edges into CSR buckets (int atomics on cursors, ~E ops total)
__global__ void scatter_k(const int* __restrict__ src, const int* __restrict__ dst,
                          int* __restrict__ cur, int* __restrict__ csr, int E, int n) {
    int e = blockIdx.x * blockDim.x + threadIdx.x;
    if (e < E) {
        int d = dst[e], s = src[e];
        if ((unsigned)d < (unsigned)n && (unsigned)s < (unsigned)n) {
            int pos = atomicAdd(&cur[d], 1);
            csr[pos] = s;
        }
    }
}

// ---------------------------------------------------------------------------
// CSR aggregation, atomic-free: one wave per dst node.
// z[i] = dinv[i] * sum_{s in in(i)} dinv[s]*x[s]  +  dinv[i]^2 * x[i]
//
// Lane-parallel metadata prefetch: lanes cooperatively load up to 64 csr
// indices + dinv weights per chunk, broadcast via __shfl. The inner loop's
// row loads then depend only on registers -> back-to-back issue, deep MLP,
// BW-bound instead of pointer-chase-latency-bound.
template <int DIM>
__global__ __launch_bounds__(256) void agg_csr_k(
    const int* __restrict__ rs, const int* __restrict__ csr,
    const float* __restrict__ xin, const float* __restrict__ dinv,
    float* __restrict__ z, int n) {
    constexpr int VEC = DIM / 64;  // 2 (DIM=128) or 4 (DIM=256)
    int wid  = (blockIdx.x * blockDim.x + threadIdx.x) >> 6;
    int lane = threadIdx.x & 63;
    int nw   = (gridDim.x * blockDim.x) >> 6;
    for (int i = wid; i < n; i += nw) {
        int j0 = rs[i], j1 = rs[i + 1];
        float acc[VEC];
#pragma unroll
        for (int v = 0; v < VEC; v++) acc[v] = 0.0f;

        for (int jb = j0; jb < j1; jb += 64) {
            int m = j1 - jb; if (m > 64) m = 64;
            int   sj = (lane < m) ? csr[jb + lane] : 0;
            float wj = (lane < m) ? dinv[sj] : 0.0f;
#pragma unroll 4
            for (int r = 0; r < m; r++) {
                int   s = __shfl(sj, r);
                float w = __shfl(wj, r);
                const float* xr = xin + (size_t)s * DIM + lane * VEC;
                if constexpr (VEC == 4) {
                    float4 a = *(const float4*)xr;
                    acc[0] += a.x * w; acc[1] += a.y * w;
                    acc[2] += a.z * w; acc[3] += a.w * w;
                } else {
                    float2 a = *(const float2*)xr;
                    acc[0] += a.x * w; acc[1] += a.y * w;
                }
            }
        }

        float di  = dinv[i];
        float di2 = di * di;
        const float* xr = xin + (size_t)i * DIM + lane * VEC;
        float* zr = z + (size_t)i * DIM + lane * VEC;
        if constexpr (VEC == 4) {
            float4 xv = *(const float4*)xr;
            float4 o;
            o.x = di * acc[0] + di2 * xv.x;
            o.y = di * acc[1] + di2 * xv.y;
            o.z = di * acc[2] + di2 * xv.z;
            o.w = di * acc[3] + di2 * xv.w;
            *(float4*)zr = o;
        } else {
            float2 xv = *(const float2*)xr;
            float2 o;
            o.x = di * acc[0] + di2 * xv.x;
            o.y = di * acc[1] + di2 * xv.y;
            *(float2*)zr = o;
        }
    }
}

// ---------------------------------------------------------------------------
// GEMM: h = z @ W + bias. One block = 32 rows x 256 cols; thread t owns
// column t; zs reads are wave-uniform broadcasts (conflict-free).
template <int K>
__global__ __launch_bounds__(256) void gcn_gemm_k(
    const float* __restrict__ z, const float* __restrict__ W,
    const float* __restrict__ bias, float* __restrict__ hout, int n) {
    constexpr int BM = 32;
    __shared__ float zs[BM][K];
    const int t  = threadIdx.x;
    const int r0 = blockIdx.x * BM;

    constexpr int NV = BM * K / 4;  // float4 elements
    for (int v = t; v < NV; v += 256) {
        int m   = v / (K / 4);
        int c   = (v % (K / 4)) * 4;
        int row = r0 + m;
        if (row < n) *(float4*)&zs[m][c] = *(const float4*)(z + (size_t)row * K + c);
        else         *(float4*)&zs[m][c] = make_float4(0.f, 0.f, 0.f, 0.f);
    }
    __syncthreads();

    float acc[BM];
    float bv = bias[t];
#pragma unroll
    for (int m = 0; m < BM; m++) acc[m] = bv;

    for (int k = 0; k < K; k += 4) {
        float w0 = W[(size_t)(k + 0) * HDIM + t];
        float w1 = W[(size_t)(k + 1) * HDIM + t];
        float w2 = W[(size_t)(k + 2) * HDIM + t];
        float w3 = W[(size_t)(k + 3) * HDIM + t];
#pragma unroll
        for (int m = 0; m < BM; m++) {
            float4 z4 = *(const float4*)&zs[m][k];  // broadcast
            acc[m] += z4.x * w0 + z4.y * w1 + z4.z * w2 + z4.w * w3;
        }
    }

#pragma unroll
    for (int m = 0; m < BM; m++) {
        int row = r0 + m;
        if (row < n) hout[(size_t)row * HDIM + t] = acc[m];
    }
}

// ---------------------------------------------------------------------------
// per-graph sum / sumsq over all nodes & channels  (one wave per node)
__global__ void ln_stats_k(const float* __restrict__ h, const int* __restrict__ batch,
                           float* __restrict__ gsum, float* __restrict__ gsq, int n) {
    int wid  = (blockIdx.x * blockDim.x + threadIdx.x) >> 6;
    int lane = threadIdx.x & 63;
    int nw   = (gridDim.x * blockDim.x) >> 6;
    for (int i = wid; i < n; i += nw) {
        float4 v = *(const float4*)(h + (size_t)i * HDIM + lane * 4);
        float s = v.x + v.y + v.z + v.w;
        float q = v.x * v.x + v.y * v.y + v.z * v.z + v.w * v.w;
        for (int o = 32; o; o >>= 1) {
            s += __shfl_down(s, o);
            q += __shfl_down(q, o);
        }
        if (lane == 0) {
            int b = batch[i];
            if (b >= 0 && b < NGRAPH) {
                unsafeAtomicAdd(&gsum[b], s);
                unsafeAtomicAdd(&gsq[b], q);
            }
        }
    }
}

// mean / rstd per graph (counts derived from last_idx of sorted batch)
__global__ void ln_fin_k(const float* __restrict__ gsum, const float* __restrict__ gsq,
                         const int* __restrict__ lastidx, float* __restrict__ mean,
                         float* __restrict__ rstd, int n) {
    int g = threadIdx.x;
    if (g >= NGRAPH) return;
    int last = lastidx[g];
    if (last < 0) last = 0; if (last >= n) last = n - 1;
    int prev = g ? lastidx[g - 1] : -1;
    if (prev < -1) prev = -1; if (prev >= n) prev = n - 1;
    float cnt = (float)(last - prev);
    if (cnt < 1.0f) cnt = 1.0f;
    float denom = cnt * (float)HDIM;
    float m = gsum[g] / denom;
    float v = gsq[g] / denom - m * m;
    if (v < 0.0f) v = 0.0f;
    mean[g] = m;
    rstd[g] = 1.0f / sqrtf(v + 1e-5f);
}

// in-place: h = tanh((h - mean)*rstd*w + b)
__global__ void ln_tanh_k(float* __restrict__ h, const int* __restrict__ batch,
                          const float* __restrict__ mean, const float* __restrict__ rstd,
                          const float* __restrict__ w, const float* __restrict__ b, int n) {
    long gid = (long)blockIdx.x * blockDim.x + threadIdx.x;
    long total = (long)n * 64;
    if (gid >= total) return;
    int i  = (int)(gid >> 6);
    int c  = (int)(gid & 63) * 4;
    int bg = batch[i];
    if (bg < 0) bg = 0; if (bg >= NGRAPH) bg = NGRAPH - 1;
    float m = mean[bg], r = rstd[bg];
    float4 v  = *(const float4*)(h + (size_t)i * HDIM + c);
    float4 w4 = *(const float4*)(w + c);
    float4 b4 = *(const float4*)(b + c);
    v.x = tanhf((v.x - m) * r * w4.x + b4.x);
    v.y = tanhf((v.y - m) * r * w4.y + b4.y);
    v.z = tanhf((v.z - m) * r * w4.z + b4.z);
    v.w = tanhf((v.w - m) * r * w4.w + b4.w);
    *(float4*)(h + (size_t)i * HDIM + c) = v;
}

// gather the 64 last-node rows of a layer output into xjk[l]
__global__ void extract_rows_k(const float* __restrict__ x, const int* __restrict__ lastidx,
                               float* __restrict__ out, int n) {
    int g = blockIdx.x, c = threadIdx.x;
    int r = lastidx[g];
    if (r < 0) r = 0; if (r >= n) r = n - 1;
    out[(size_t)g * HDIM + c] = x[(size_t)r * HDIM + c];
}

// ---------------------------------------------------------------------------
// head: JK-cat [768] @ jk_w + jk_b -> tanh(fc1) -> fc2, one block per graph
__global__ __launch_bounds__(256) void final_mlp_k(
    const float* __restrict__ xjk,  // [3][64][256]
    const float* __restrict__ jk_w, const float* __restrict__ jk_b,
    const float* __restrict__ fc1_w, const float* __restrict__ fc1_b,
    const float* __restrict__ fc2_w, const float* __restrict__ fc2_b,
    float* __restrict__ out) {
    __shared__ float vec[3 * HDIM];
    __shared__ float h1[HDIM];
    __shared__ float h2[128];
    int g = blockIdx.x, t = threadIdx.x;
    vec[t]            = xjk[(size_t)0 * NGRAPH * HDIM + (size_t)g * HDIM + t];
    vec[HDIM + t]     = xjk[(size_t)1 * NGRAPH * HDIM + (size_t)g * HDIM + t];
    vec[2 * HDIM + t] = xjk[(size_t)2 * NGRAPH * HDIM + (size_t)g * HDIM + t];
    __syncthreads();
    float a = jk_b[t];
    for (int k = 0; k < 3 * HDIM; k++) a += vec[k] * jk_w[(size_t)k * HDIM + t];
    h1[t] = a;
    __syncthreads();
    if (t < 128) {
        float a2 = fc1_b[t];
        for (int k = 0; k < HDIM; k++) a2 += h1[k] * fc1_w[(size_t)k * 128 + t];
        h2[t] = tanhf(a2);
    }
    __syncthreads();
    if (t < 64) {
        float a3 = h2[t] * fc2_w[t] + h2[t + 64] * fc2_w[t + 64];
        for (int o = 32; o; o >>= 1) a3 += __shfl_down(a3, o);
        if (t == 0) out[g] = a3 + fc2_b[0];
    }
}

// ---------------------------------------------------------------------------
extern "C" void kernel_launch(void* const* d_in, const int* in_sizes, int n_in,
                              void* d_out, int out_size, void* d_ws, size_t ws_size,
                              hipStream_t stream) {
    const float* x    = (const float*)d_in[0];
    const float* W1   = (const float*)d_in[1];
    const float* b1   = (const float*)d_in[2];
    const float* ln1w = (const float*)d_in[3];
    const float* ln1b = (const float*)d_in[4];
    const float* W2   = (const float*)d_in[5];
    const float* b2   = (const float*)d_in[6];
    const float* ln2w = (const float*)d_in[7];
    const float* ln2b = (const float*)d_in[8];
    const float* W3   = (const float*)d_in[9];
    const float* b3   = (const float*)d_in[10];
    const float* ln3w = (const float*)d_in[11];
    const float* ln3b = (const float*)d_in[12];
    const float* jkw  = (const float*)d_in[13];
    const float* jkb  = (const float*)d_in[14];
    const float* fc1w = (const float*)d_in[15];
    const float* fc1b = (const float*)d_in[16];
    const float* fc2w = (const float*)d_in[17];
    const float* fc2b = (const float*)d_in[18];
    const int*  eidx  = (const int*)d_in[19];
    const int*  batch = (const int*)d_in[20];

    const int E = in_sizes[19] / 2;
    const int n = in_sizes[20];

    const int* src = eidx;
    const int* dst = eidx + E;

    // workspace carve-up (~213 MB):
    char* base = (char*)d_ws;
    size_t o = 0;
    auto alloc = [&](size_t bytes) { void* p = base + o; o += (bytes + 255) & ~(size_t)255; return p; };
    float* bufZ = (float*)alloc((size_t)n * HDIM * 4);
    float* bufH = (float*)alloc((size_t)n * HDIM * 4);
    int*   csr  = (int*)alloc((size_t)E * 4);
    int*   rs   = (int*)alloc((size_t)(n + 1) * 4);
    int*   cur  = (int*)alloc((size_t)n * 4);
    int*   degi = (int*)alloc((size_t)n * 4);
    float* dinv = (float*)alloc((size_t)n * 4);
    int*   part = (int*)alloc(1024 * 4);
    float* xjk  = (float*)alloc((size_t)3 * NGRAPH * HDIM * 4);
    int*   lidx = (int*)alloc(NGRAPH * 4);
    float* gsum = (float*)alloc(NGRAPH * 4);
    float* gsq  = (float*)alloc(NGRAPH * 4);
    float* mean = (float*)alloc(NGRAPH * 4);
    float* rstd = (float*)alloc(NGRAPH * 4);
    (void)ws_size;

    float* out = (float*)d_out;
    const int GB = (n + 31) / 32;                       // gemm blocks
    const int NB = (n + SCAN_CHUNK - 1) / SCAN_CHUNK;   // scan blocks (49)
    const int AB = 2048;                                // agg blocks (8192 waves = 32/CU)

    // --- CSR build + degrees + last-node indices (once per call) ---
    hipMemsetAsync(degi, 0, (size_t)n * 4, stream);
    hipMemsetAsync(lidx, 0, NGRAPH * 4, stream);
    deg_count_k<<<(E + 255) / 256, 256, 0, stream>>>(dst, degi, E, n);
    dinv_k<<<(n + 255) / 256, 256, 0, stream>>>(degi, dinv, n);
    last_idx_k<<<(n + 255) / 256, 256, 0, stream>>>(batch, lidx, n);
    scan1_k<<<NB, 256, 0, stream>>>(degi, part, n);
    scan2_k<<<1, 1024, 0, stream>>>(part, NB, rs, n);
    scan3_k<<<NB, 256, 0, stream>>>(degi, part, rs, cur, n);
    scatter_k<<<(E + 255) / 256, 256, 0, stream>>>(src, dst, cur, csr, E, n);

    // ---------------- layer 1 (K = 128) ----------------
    agg_csr_k<128><<<AB, 256, 0, stream>>>(rs, csr, x, dinv, bufZ, n);
    gcn_gemm_k<128><<<GB, 256, 0, stream>>>(bufZ, W1, b1, bufH, n);
    hipMemsetAsync(gsum, 0, 2 * NGRAPH * 4, stream);  // gsum+gsq contiguous
    ln_stats_k<<<2048, 256, 0, stream>>>(bufH, batch, gsum, gsq, n);
    ln_fin_k<<<1, 64, 0, stream>>>(gsum, gsq, lidx, mean, rstd, n);
    ln_tanh_k<<<(int)(((long)n * 64 + 255) / 256), 256, 0, stream>>>(bufH, batch, mean, rstd, ln1w, ln1b, n);
    extract_rows_k<<<NGRAPH, 256, 0, stream>>>(bufH, lidx, xjk + 0 * NGRAPH * HDIM, n);

    // ---------------- layer 2 ----------------
    agg_csr_k<256><<<AB, 256, 0, stream>>>(rs, csr, bufH, dinv, bufZ, n);
    gcn_gemm_k<256><<<GB, 256, 0, stream>>>(bufZ, W2, b2, bufH, n);
    hipMemsetAsync(gsum, 0, 2 * NGRAPH * 4, stream);
    ln_stats_k<<<2048, 256, 0, stream>>>(bufH, batch, gsum, gsq, n);
    ln_fin_k<<<1, 64, 0, stream>>>(gsum, gsq, lidx, mean, rstd, n);
    ln_tanh_k<<<(int)(((long)n * 64 + 255) / 256), 256, 0, stream>>>(bufH, batch, mean, rstd, ln2w, ln2b, n);
    extract_rows_k<<<NGRAPH, 256, 0, stream>>>(bufH, lidx, xjk + 1 * NGRAPH * HDIM, n);

    // ---------------- layer 3 ----------------
    agg_csr_k<256><<<AB, 256, 0, stream>>>(rs, csr, bufH, dinv, bufZ, n);
    gcn_gemm_k<256><<<GB, 256, 0, stream>>>(bufZ, W3, b3, bufH, n);
    hipMemsetAsync(gsum, 0, 2 * NGRAPH * 4, stream);
    ln_stats_k<<<2048, 256, 0, stream>>>(bufH, batch, gsum, gsq, n);
    ln_fin_k<<<1, 64, 0, stream>>>(gsum, gsq, lidx, mean, rstd, n);
    ln_tanh_k<<<(int)(((long)n * 64 + 255) / 256), 256, 0, stream>>>(bufH, batch, mean, rstd, ln3w, ln3b, n);
    extract_rows_k<<<NGRAPH, 256, 0, stream>>>(bufH, lidx, xjk + 2 * NGRAPH * HDIM, n);

    // ---------------- head (64 nodes only) ----------------
    final_mlp_k<<<NGRAPH, 256, 0, stream>>>(xjk, jkw, jkb, fc1w, fc1b, fc2w, fc2b, out);
}

// Round 6
// 1981.410 us; speedup vs baseline: 2.1239x; 2.1239x over previous
//
#include <hip/hip_runtime.h>
#include <hip/hip_bf16.h>
#include <math.h>

// Problem constants (from reference): N=100000 nodes, E=1600000 edges,
// D=128 in-feat, H=256 hidden, B=64 graphs. Output: [B,1] fp32.
// R5: baseline 4208us. ln_stats_k was 3x805us (57%) — same-address fp32
// atomic serialization (200k atomics -> 64 addrs, VALUBusy 0.6%).
// Fix: contiguous-slab blocks + LDS per-graph accumulation -> ~4k global atomics.
#define HDIM 256
#define NGRAPH 64
#define SCAN_CHUNK 2048  // 256 threads x 8 elems

// ---------------------------------------------------------------------------
// in-degree count (int atomics)
__global__ void deg_count_k(const int* __restrict__ dst, int* __restrict__ deg, int E, int n) {
    int i = blockIdx.x * blockDim.x + threadIdx.x;
    if (i < E) {
        int d = dst[i];
        if ((unsigned)d < (unsigned)n) atomicAdd(&deg[d], 1);
    }
}

// dinv[i] = 1/sqrt(in_deg[i] + 1)
__global__ void dinv_k(const int* __restrict__ deg, float* __restrict__ dinv, int n) {
    int i = blockIdx.x * blockDim.x + threadIdx.x;
    if (i < n) dinv[i] = 1.0f / sqrtf((float)deg[i] + 1.0f);
}

// last node index of each (sorted, consecutive) graph id
__global__ void last_idx_k(const int* __restrict__ batch, int* __restrict__ lastidx, int n) {
    int i = blockIdx.x * blockDim.x + threadIdx.x;
    if (i < n) {
        int b = batch[i];
        if ((i == n - 1 || batch[i + 1] != b) && b >= 0 && b < NGRAPH) lastidx[b] = i;
    }
}

// --------------------------- exclusive prefix scan -------------------------
// scan1: per-block (2048-elem chunk) sums
__global__ __launch_bounds__(256) void scan1_k(const int* __restrict__ deg,
                                               int* __restrict__ partial, int n) {
    __shared__ int sm[256];
    int t = threadIdx.x;
    int base = blockIdx.x * SCAN_CHUNK + t * 8;
    int s = 0;
#pragma unroll
    for (int j = 0; j < 8; j++) { int idx = base + j; if (idx < n) s += deg[idx]; }
    sm[t] = s; __syncthreads();
    for (int o = 128; o; o >>= 1) { if (t < o) sm[t] += sm[t + o]; __syncthreads(); }
    if (t == 0) partial[blockIdx.x] = sm[0];
}

// scan2: single block, exclusive scan of block partials (nb <= 1024); rs[n] = total
__global__ __launch_bounds__(1024) void scan2_k(int* __restrict__ partial, int nb,
                                                int* __restrict__ rs, int n) {
    __shared__ int sm[1024];
    int t = threadIdx.x;
    int v = (t < nb) ? partial[t] : 0;
    sm[t] = v; __syncthreads();
    for (int o = 1; o < 1024; o <<= 1) {
        int add = (t >= o) ? sm[t - o] : 0;
        __syncthreads();
        sm[t] += add;
        __syncthreads();
    }
    if (t < nb) partial[t] = sm[t] - v;  // exclusive block offset
    if (t == nb - 1) rs[n] = sm[t];      // total edge count
}

// scan3: write row_start (exclusive prefix) + cursor copy
__global__ __launch_bounds__(256) void scan3_k(const int* __restrict__ deg,
                                               const int* __restrict__ partial,
                                               int* __restrict__ rs, int* __restrict__ cur, int n) {
    __shared__ int sm[256];
    int t = threadIdx.x;
    int base = blockIdx.x * SCAN_CHUNK + t * 8;
    int loc[8]; int s = 0;
#pragma unroll
    for (int j = 0; j < 8; j++) {
        int idx = base + j;
        loc[j] = (idx < n) ? deg[idx] : 0;
        s += loc[j];
    }
    sm[t] = s; __syncthreads();
    int v = s;
    for (int o = 1; o < 256; o <<= 1) {
        int add = (t >= o) ? sm[t - o] : 0;
        __syncthreads();
        sm[t] += add;
        __syncthreads();
    }
    int run = partial[blockIdx.x] + sm[t] - v;  // exclusive prefix for this thread
#pragma unroll
    for (int j = 0; j < 8; j++) {
        int idx = base + j;
        if (idx < n) { rs[idx] = run; cur[idx] = run; }
        run += loc[j];
    }
}

// scatter edges into CSR buckets (int atomics on cursors, ~E ops total)
__global__ void scatter_k(const int* __restrict__ src, const int* __restrict__ dst,
                          int* __restrict__ cur, int* __restrict__ csr, int E, int n) {
    int e = blockIdx.x * blockDim.x + threadIdx.x;
    if (e < E) {
        int d = dst[e], s = src[e];
        if ((unsigned)d < (unsigned)n && (unsigned)s < (unsigned)n) {
            int pos = atomicAdd(&cur[d], 1);
            csr[pos] = s;
        }
    }
}

// ---------------------------------------------------------------------------
// CSR aggregation, atomic-free: one wave per dst node.
// z[i] = dinv[i] * sum_{s in in(i)} dinv[s]*x[s]  +  dinv[i]^2 * x[i]
template <int DIM>
__global__ __launch_bounds__(256) void agg_csr_k(
    const int* __restrict__ rs, const int* __restrict__ csr,
    const float* __restrict__ xin, const float* __restrict__ dinv,
    float* __restrict__ z, int n) {
    constexpr int VEC = DIM / 64;  // 2 (DIM=128) or 4 (DIM=256)
    int wid  = (blockIdx.x * blockDim.x + threadIdx.x) >> 6;
    int lane = threadIdx.x & 63;
    int nw   = (gridDim.x * blockDim.x) >> 6;
    for (int i = wid; i < n; i += nw) {
        int j0 = rs[i], j1 = rs[i + 1];
        float acc[VEC];
#pragma unroll
        for (int v = 0; v < VEC; v++) acc[v] = 0.0f;

        for (int jb = j0; jb < j1; jb += 64) {
            int m = j1 - jb; if (m > 64) m = 64;
            int   sj = (lane < m) ? csr[jb + lane] : 0;
            float wj = (lane < m) ? dinv[sj] : 0.0f;
#pragma unroll 4
            for (int r = 0; r < m; r++) {
                int   s = __shfl(sj, r);
                float w = __shfl(wj, r);
                const float* xr = xin + (size_t)s * DIM + lane * VEC;
                if constexpr (VEC == 4) {
                    float4 a = *(const float4*)xr;
                    acc[0] += a.x * w; acc[1] += a.y * w;
                    acc[2] += a.z * w; acc[3] += a.w * w;
                } else {
                    float2 a = *(const float2*)xr;
                    acc[0] += a.x * w; acc[1] += a.y * w;
                }
            }
        }

        float di  = dinv[i];
        float di2 = di * di;
        const float* xr = xin + (size_t)i * DIM + lane * VEC;
        float* zr = z + (size_t)i * DIM + lane * VEC;
        if constexpr (VEC == 4) {
            float4 xv = *(const float4*)xr;
            float4 o;
            o.x = di * acc[0] + di2 * xv.x;
            o.y = di * acc[1] + di2 * xv.y;
            o.z = di * acc[2] + di2 * xv.z;
            o.w = di * acc[3] + di2 * xv.w;
            *(float4*)zr = o;
        } else {
            float2 xv = *(const float2*)xr;
            float2 o;
            o.x = di * acc[0] + di2 * xv.x;
            o.y = di * acc[1] + di2 * xv.y;
            *(float2*)zr = o;
        }
    }
}

// ---------------------------------------------------------------------------
// GEMM: h = z @ W + bias. One block = 32 rows x 256 cols; thread t owns
// column t; zs reads are wave-uniform broadcasts (conflict-free).
template <int K>
__global__ __launch_bounds__(256) void gcn_gemm_k(
    const float* __restrict__ z, const float* __restrict__ W,
    const float* __restrict__ bias, float* __restrict__ hout, int n) {
    constexpr int BM = 32;
    __shared__ float zs[BM][K];
    const int t  = threadIdx.x;
    const int r0 = blockIdx.x * BM;

    constexpr int NV = BM * K / 4;  // float4 elements
    for (int v = t; v < NV; v += 256) {
        int m   = v / (K / 4);
        int c   = (v % (K / 4)) * 4;
        int row = r0 + m;
        if (row < n) *(float4*)&zs[m][c] = *(const float4*)(z + (size_t)row * K + c);
        else         *(float4*)&zs[m][c] = make_float4(0.f, 0.f, 0.f, 0.f);
    }
    __syncthreads();

    float acc[BM];
    float bv = bias[t];
#pragma unroll
    for (int m = 0; m < BM; m++) acc[m] = bv;

    for (int k = 0; k < K; k += 4) {
        float w0 = W[(size_t)(k + 0) * HDIM + t];
        float w1 = W[(size_t)(k + 1) * HDIM + t];
        float w2 = W[(size_t)(k + 2) * HDIM + t];
        float w3 = W[(size_t)(k + 3) * HDIM + t];
#pragma unroll
        for (int m = 0; m < BM; m++) {
            float4 z4 = *(const float4*)&zs[m][k];  // broadcast
            acc[m] += z4.x * w0 + z4.y * w1 + z4.z * w2 + z4.w * w3;
        }
    }

#pragma unroll
    for (int m = 0; m < BM; m++) {
        int row = r0 + m;
        if (row < n) hout[(size_t)row * HDIM + t] = acc[m];
    }
}

// ---------------------------------------------------------------------------
// per-graph sum/sumsq, hierarchical: contiguous node slab per block,
// LDS per-graph accumulators (ds_add atomics), few global atomics per block.
__global__ __launch_bounds__(256) void ln_stats_k(
    const float* __restrict__ h, const int* __restrict__ batch,
    float* __restrict__ gsum, float* __restrict__ gsq, int n, int npb) {
    __shared__ float lsum[NGRAPH], lsq[NGRAPH];
    int t = threadIdx.x;
    if (t < NGRAPH) { lsum[t] = 0.0f; lsq[t] = 0.0f; }
    __syncthreads();
    int wv = t >> 6, lane = t & 63;
    int i0 = blockIdx.x * npb;
    int i1 = i0 + npb; if (i1 > n) i1 = n;
    for (int i = i0 + wv; i < i1; i += 4) {
        float4 v = *(const float4*)(h + (size_t)i * HDIM + lane * 4);
        float s = v.x + v.y + v.z + v.w;
        float q = v.x * v.x + v.y * v.y + v.z * v.z + v.w * v.w;
        for (int o = 32; o; o >>= 1) {
            s += __shfl_down(s, o);
            q += __shfl_down(q, o);
        }
        if (lane == 0) {
            int b = batch[i];
            if (b < 0) b = 0; if (b >= NGRAPH) b = NGRAPH - 1;
            atomicAdd(&lsum[b], s);  // LDS atomic (ds_add)
            atomicAdd(&lsq[b], q);
        }
    }
    __syncthreads();
    if (t < NGRAPH) {
        float s = lsum[t], q = lsq[t];
        if (s != 0.0f || q != 0.0f) {  // only graphs this slab touched
            unsafeAtomicAdd(&gsum[t], s);
            unsafeAtomicAdd(&gsq[t], q);
        }
    }
}

// mean / rstd per graph (counts derived from last_idx of sorted batch)
__global__ void ln_fin_k(const float* __restrict__ gsum, const float* __restrict__ gsq,
                         const int* __restrict__ lastidx, float* __restrict__ mean,
                         float* __restrict__ rstd, int n) {
    int g = threadIdx.x;
    if (g >= NGRAPH) return;
    int last = lastidx[g];
    if (last < 0) last = 0; if (last >= n) last = n - 1;
    int prev = g ? lastidx[g - 1] : -1;
    if (prev < -1) prev = -1; if (prev >= n) prev = n - 1;
    float cnt = (float)(last - prev);
    if (cnt < 1.0f) cnt = 1.0f;
    float denom = cnt * (float)HDIM;
    float m = gsum[g] / denom;
    float v = gsq[g] / denom - m * m;
    if (v < 0.0f) v = 0.0f;
    mean[g] = m;
    rstd[g] = 1.0f / sqrtf(v + 1e-5f);
}

// in-place: h = tanh((h - mean)*rstd*w + b)
__global__ void ln_tanh_k(float* __restrict__ h, const int* __restrict__ batch,
                          const float* __restrict__ mean, const float* __restrict__ rstd,
                          const float* __restrict__ w, const float* __restrict__ b, int n) {
    long gid = (long)blockIdx.x * blockDim.x + threadIdx.x;
    long total = (long)n * 64;
    if (gid >= total) return;
    int i  = (int)(gid >> 6);
    int c  = (int)(gid & 63) * 4;
    int bg = batch[i];
    if (bg < 0) bg = 0; if (bg >= NGRAPH) bg = NGRAPH - 1;
    float m = mean[bg], r = rstd[bg];
    float4 v  = *(const float4*)(h + (size_t)i * HDIM + c);
    float4 w4 = *(const float4*)(w + c);
    float4 b4 = *(const float4*)(b + c);
    v.x = tanhf((v.x - m) * r * w4.x + b4.x);
    v.y = tanhf((v.y - m) * r * w4.y + b4.y);
    v.z = tanhf((v.z - m) * r * w4.z + b4.z);
    v.w = tanhf((v.w - m) * r * w4.w + b4.w);
    *(float4*)(h + (size_t)i * HDIM + c) = v;
}

// gather the 64 last-node rows of a layer output into xjk[l]
__global__ void extract_rows_k(const float* __restrict__ x, const int* __restrict__ lastidx,
                               float* __restrict__ out, int n) {
    int g = blockIdx.x, c = threadIdx.x;
    int r = lastidx[g];
    if (r < 0) r = 0; if (r >= n) r = n - 1;
    out[(size_t)g * HDIM + c] = x[(size_t)r * HDIM + c];
}

// ---------------------------------------------------------------------------
// head: JK-cat [768] @ jk_w + jk_b -> tanh(fc1) -> fc2, one block per graph
__global__ __launch_bounds__(256) void final_mlp_k(
    const float* __restrict__ xjk,  // [3][64][256]
    const float* __restrict__ jk_w, const float* __restrict__ jk_b,
    const float* __restrict__ fc1_w, const float* __restrict__ fc1_b,
    const float* __restrict__ fc2_w, const float* __restrict__ fc2_b,
    float* __restrict__ out) {
    __shared__ float vec[3 * HDIM];
    __shared__ float h1[HDIM];
    __shared__ float h2[128];
    int g = blockIdx.x, t = threadIdx.x;
    vec[t]            = xjk[(size_t)0 * NGRAPH * HDIM + (size_t)g * HDIM + t];
    vec[HDIM + t]     = xjk[(size_t)1 * NGRAPH * HDIM + (size_t)g * HDIM + t];
    vec[2 * HDIM + t] = xjk[(size_t)2 * NGRAPH * HDIM + (size_t)g * HDIM + t];
    __syncthreads();
    float a = jk_b[t];
    for (int k = 0; k < 3 * HDIM; k++) a += vec[k] * jk_w[(size_t)k * HDIM + t];
    h1[t] = a;
    __syncthreads();
    if (t < 128) {
        float a2 = fc1_b[t];
        for (int k = 0; k < HDIM; k++) a2 += h1[k] * fc1_w[(size_t)k * 128 + t];
        h2[t] = tanhf(a2);
    }
    __syncthreads();
    if (t < 64) {
        float a3 = h2[t] * fc2_w[t] + h2[t + 64] * fc2_w[t + 64];
        for (int o = 32; o; o >>= 1) a3 += __shfl_down(a3, o);
        if (t == 0) out[g] = a3 + fc2_b[0];
    }
}

// ---------------------------------------------------------------------------
extern "C" void kernel_launch(void* const* d_in, const int* in_sizes, int n_in,
                              void* d_out, int out_size, void* d_ws, size_t ws_size,
                              hipStream_t stream) {
    const float* x    = (const float*)d_in[0];
    const float* W1   = (const float*)d_in[1];
    const float* b1   = (const float*)d_in[2];
    const float* ln1w = (const float*)d_in[3];
    const float* ln1b = (const float*)d_in[4];
    const float* W2   = (const float*)d_in[5];
    const float* b2   = (const float*)d_in[6];
    const float* ln2w = (const float*)d_in[7];
    const float* ln2b = (const float*)d_in[8];
    const float* W3   = (const float*)d_in[9];
    const float* b3   = (const float*)d_in[10];
    const float* ln3w = (const float*)d_in[11];
    const float* ln3b = (const float*)d_in[12];
    const float* jkw  = (const float*)d_in[13];
    const float* jkb  = (const float*)d_in[14];
    const float* fc1w = (const float*)d_in[15];
    const float* fc1b = (const float*)d_in[16];
    const float* fc2w = (const float*)d_in[17];
    const float* fc2b = (const float*)d_in[18];
    const int*  eidx  = (const int*)d_in[19];
    const int*  batch = (const int*)d_in[20];

    const int E = in_sizes[19] / 2;
    const int n = in_sizes[20];

    const int* src = eidx;
    const int* dst = eidx + E;

    // workspace carve-up (~213 MB):
    char* base = (char*)d_ws;
    size_t o = 0;
    auto alloc = [&](size_t bytes) { void* p = base + o; o += (bytes + 255) & ~(size_t)255; return p; };
    float* bufZ = (float*)alloc((size_t)n * HDIM * 4);
    float* bufH = (float*)alloc((size_t)n * HDIM * 4);
    int*   csr  = (int*)alloc((size_t)E * 4);
    int*   rs   = (int*)alloc((size_t)(n + 1) * 4);
    int*   cur  = (int*)alloc((size_t)n * 4);
    int*   degi = (int*)alloc((size_t)n * 4);
    float* dinv = (float*)alloc((size_t)n * 4);
    int*   part = (int*)alloc(1024 * 4);
    float* xjk  = (float*)alloc((size_t)3 * NGRAPH * HDIM * 4);
    int*   lidx = (int*)alloc(NGRAPH * 4);
    float* gsum = (float*)alloc(NGRAPH * 4);
    float* gsq  = (float*)alloc(NGRAPH * 4);
    float* mean = (float*)alloc(NGRAPH * 4);
    float* rstd = (float*)alloc(NGRAPH * 4);
    (void)ws_size;

    float* out = (float*)d_out;
    const int GB = (n + 31) / 32;                       // gemm blocks
    const int NB = (n + SCAN_CHUNK - 1) / SCAN_CHUNK;   // scan blocks (49)
    const int AB = 2048;                                // agg blocks (8192 waves = 32/CU)
    const int SB = 1024;                                // ln_stats blocks
    const int NPB = (n + SB - 1) / SB;                  // nodes per stats block (~98)

    // --- CSR build + degrees + last-node indices (once per call) ---
    hipMemsetAsync(degi, 0, (size_t)n * 4, stream);
    hipMemsetAsync(lidx, 0, NGRAPH * 4, stream);
    deg_count_k<<<(E + 255) / 256, 256, 0, stream>>>(dst, degi, E, n);
    dinv_k<<<(n + 255) / 256, 256, 0, stream>>>(degi, dinv, n);
    last_idx_k<<<(n + 255) / 256, 256, 0, stream>>>(batch, lidx, n);
    scan1_k<<<NB, 256, 0, stream>>>(degi, part, n);
    scan2_k<<<1, 1024, 0, stream>>>(part, NB, rs, n);
    scan3_k<<<NB, 256, 0, stream>>>(degi, part, rs, cur, n);
    scatter_k<<<(E + 255) / 256, 256, 0, stream>>>(src, dst, cur, csr, E, n);

    // ---------------- layer 1 (K = 128) ----------------
    agg_csr_k<128><<<AB, 256, 0, stream>>>(rs, csr, x, dinv, bufZ, n);
    gcn_gemm_k<128><<<GB, 256, 0, stream>>>(bufZ, W1, b1, bufH, n);
    hipMemsetAsync(gsum, 0, 2 * NGRAPH * 4, stream);  // gsum+gsq contiguous
    ln_stats_k<<<SB, 256, 0, stream>>>(bufH, batch, gsum, gsq, n, NPB);
    ln_fin_k<<<1, 64, 0, stream>>>(gsum, gsq, lidx, mean, rstd, n);
    ln_tanh_k<<<(int)(((long)n * 64 + 255) / 256), 256, 0, stream>>>(bufH, batch, mean, rstd, ln1w, ln1b, n);
    extract_rows_k<<<NGRAPH, 256, 0, stream>>>(bufH, lidx, xjk + 0 * NGRAPH * HDIM, n);

    // ---------------- layer 2 ----------------
    agg_csr_k<256><<<AB, 256, 0, stream>>>(rs, csr, bufH, dinv, bufZ, n);
    gcn_gemm_k<256><<<GB, 256, 0, stream>>>(bufZ, W2, b2, bufH, n);
    hipMemsetAsync(gsum, 0, 2 * NGRAPH * 4, stream);
    ln_stats_k<<<SB, 256, 0, stream>>>(bufH, batch, gsum, gsq, n, NPB);
    ln_fin_k<<<1, 64, 0, stream>>>(gsum, gsq, lidx, mean, rstd, n);
    ln_tanh_k<<<(int)(((long)n * 64 + 255) / 256), 256, 0, stream>>>(bufH, batch, mean, rstd, ln2w, ln2b, n);
    extract_rows_k<<<NGRAPH, 256, 0, stream>>>(bufH, lidx, xjk + 1 * NGRAPH * HDIM, n);

    // ---------------- layer 3 ----------------
    agg_csr_k<256><<<AB, 256, 0, stream>>>(rs, csr, bufH, dinv, bufZ, n);
    gcn_gemm_k<256><<<GB, 256, 0, stream>>>(bufZ, W3, b3, bufH, n);
    hipMemsetAsync(gsum, 0, 2 * NGRAPH * 4, stream);
    ln_stats_k<<<SB, 256, 0, stream>>>(bufH, batch, gsum, gsq, n, NPB);
    ln_fin_k<<<1, 64, 0, stream>>>(gsum, gsq, lidx, mean, rstd, n);
    ln_tanh_k<<<(int)(((long)n * 64 + 255) / 256), 256, 0, stream>>>(bufH, batch, mean, rstd, ln3w, ln3b, n);
    extract_rows_k<<<NGRAPH, 256, 0, stream>>>(bufH, lidx, xjk + 2 * NGRAPH * HDIM, n);

    // ---------------- head (64 nodes only) ----------------
    final_mlp_k<<<NGRAPH, 256, 0, stream>>>(xjk, jkw, jkb, fc1w, fc1b, fc2w, fc2b, out);
}

// Round 7
// 1719.372 us; speedup vs baseline: 2.4476x; 1.1524x over previous
//
#include <hip/hip_runtime.h>
#include <hip/hip_bf16.h>
#include <math.h>

// Problem constants (from reference): N=100000 nodes, E=1600000 edges,
// D=128 in-feat, H=256 hidden, B=64 graphs. Output: [B,1] fp32.
// R5: 4208us baseline. R6: 1981us (ln_stats LDS-hierarchical fix, -53%).
// R7: gcn_gemm was LDS-pipe-bound (25.6M broadcast ds_read_b128/GEMM ~ 333us
// ~= measured 348us). Fix: 4col x 8row register tiling -> ds_reads / 4.
#define HDIM 256
#define NGRAPH 64
#define SCAN_CHUNK 2048  // 256 threads x 8 elems

// ---------------------------------------------------------------------------
// in-degree count (int atomics)
__global__ void deg_count_k(const int* __restrict__ dst, int* __restrict__ deg, int E, int n) {
    int i = blockIdx.x * blockDim.x + threadIdx.x;
    if (i < E) {
        int d = dst[i];
        if ((unsigned)d < (unsigned)n) atomicAdd(&deg[d], 1);
    }
}

// dinv[i] = 1/sqrt(in_deg[i] + 1)
__global__ void dinv_k(const int* __restrict__ deg, float* __restrict__ dinv, int n) {
    int i = blockIdx.x * blockDim.x + threadIdx.x;
    if (i < n) dinv[i] = 1.0f / sqrtf((float)deg[i] + 1.0f);
}

// last node index of each (sorted, consecutive) graph id
__global__ void last_idx_k(const int* __restrict__ batch, int* __restrict__ lastidx, int n) {
    int i = blockIdx.x * blockDim.x + threadIdx.x;
    if (i < n) {
        int b = batch[i];
        if ((i == n - 1 || batch[i + 1] != b) && b >= 0 && b < NGRAPH) lastidx[b] = i;
    }
}

// --------------------------- exclusive prefix scan -------------------------
__global__ __launch_bounds__(256) void scan1_k(const int* __restrict__ deg,
                                               int* __restrict__ partial, int n) {
    __shared__ int sm[256];
    int t = threadIdx.x;
    int base = blockIdx.x * SCAN_CHUNK + t * 8;
    int s = 0;
#pragma unroll
    for (int j = 0; j < 8; j++) { int idx = base + j; if (idx < n) s += deg[idx]; }
    sm[t] = s; __syncthreads();
    for (int o = 128; o; o >>= 1) { if (t < o) sm[t] += sm[t + o]; __syncthreads(); }
    if (t == 0) partial[blockIdx.x] = sm[0];
}

__global__ __launch_bounds__(1024) void scan2_k(int* __restrict__ partial, int nb,
                                                int* __restrict__ rs, int n) {
    __shared__ int sm[1024];
    int t = threadIdx.x;
    int v = (t < nb) ? partial[t] : 0;
    sm[t] = v; __syncthreads();
    for (int o = 1; o < 1024; o <<= 1) {
        int add = (t >= o) ? sm[t - o] : 0;
        __syncthreads();
        sm[t] += add;
        __syncthreads();
    }
    if (t < nb) partial[t] = sm[t] - v;  // exclusive block offset
    if (t == nb - 1) rs[n] = sm[t];      // total edge count
}

__global__ __launch_bounds__(256) void scan3_k(const int* __restrict__ deg,
                                               const int* __restrict__ partial,
                                               int* __restrict__ rs, int* __restrict__ cur, int n) {
    __shared__ int sm[256];
    int t = threadIdx.x;
    int base = blockIdx.x * SCAN_CHUNK + t * 8;
    int loc[8]; int s = 0;
#pragma unroll
    for (int j = 0; j < 8; j++) {
        int idx = base + j;
        loc[j] = (idx < n) ? deg[idx] : 0;
        s += loc[j];
    }
    sm[t] = s; __syncthreads();
    int v = s;
    for (int o = 1; o < 256; o <<= 1) {
        int add = (t >= o) ? sm[t - o] : 0;
        __syncthreads();
        sm[t] += add;
        __syncthreads();
    }
    int run = partial[blockIdx.x] + sm[t] - v;  // exclusive prefix for this thread
#pragma unroll
    for (int j = 0; j < 8; j++) {
        int idx = base + j;
        if (idx < n) { rs[idx] = run; cur[idx] = run; }
        run += loc[j];
    }
}

// scatter edges into CSR buckets (int atomics on cursors, ~E ops total)
__global__ void scatter_k(const int* __restrict__ src, const int* __restrict__ dst,
                          int* __restrict__ cur, int* __restrict__ csr, int E, int n) {
    int e = blockIdx.x * blockDim.x + threadIdx.x;
    if (e < E) {
        int d = dst[e], s = src[e];
        if ((unsigned)d < (unsigned)n && (unsigned)s < (unsigned)n) {
            int pos = atomicAdd(&cur[d], 1);
            csr[pos] = s;
        }
    }
}

// ---------------------------------------------------------------------------
// CSR aggregation, atomic-free: one wave per dst node.
// z[i] = dinv[i] * sum_{s in in(i)} dinv[s]*x[s]  +  dinv[i]^2 * x[i]
template <int DIM>
__global__ __launch_bounds__(256) void agg_csr_k(
    const int* __restrict__ rs, const int* __restrict__ csr,
    const float* __restrict__ xin, const float* __restrict__ dinv,
    float* __restrict__ z, int n) {
    constexpr int VEC = DIM / 64;  // 2 (DIM=128) or 4 (DIM=256)
    int wid  = (blockIdx.x * blockDim.x + threadIdx.x) >> 6;
    int lane = threadIdx.x & 63;
    int nw   = (gridDim.x * blockDim.x) >> 6;
    for (int i = wid; i < n; i += nw) {
        int j0 = rs[i], j1 = rs[i + 1];
        float acc[VEC];
#pragma unroll
        for (int v = 0; v < VEC; v++) acc[v] = 0.0f;

        for (int jb = j0; jb < j1; jb += 64) {
            int m = j1 - jb; if (m > 64) m = 64;
            int   sj = (lane < m) ? csr[jb + lane] : 0;
            float wj = (lane < m) ? dinv[sj] : 0.0f;
#pragma unroll 4
            for (int r = 0; r < m; r++) {
                int   s = __shfl(sj, r);
                float w = __shfl(wj, r);
                const float* xr = xin + (size_t)s * DIM + lane * VEC;
                if constexpr (VEC == 4) {
                    float4 a = *(const float4*)xr;
                    acc[0] += a.x * w; acc[1] += a.y * w;
                    acc[2] += a.z * w; acc[3] += a.w * w;
                } else {
                    float2 a = *(const float2*)xr;
                    acc[0] += a.x * w; acc[1] += a.y * w;
                }
            }
        }

        float di  = dinv[i];
        float di2 = di * di;
        const float* xr = xin + (size_t)i * DIM + lane * VEC;
        float* zr = z + (size_t)i * DIM + lane * VEC;
        if constexpr (VEC == 4) {
            float4 xv = *(const float4*)xr;
            float4 o;
            o.x = di * acc[0] + di2 * xv.x;
            o.y = di * acc[1] + di2 * xv.y;
            o.z = di * acc[2] + di2 * xv.z;
            o.w = di * acc[3] + di2 * xv.w;
            *(float4*)zr = o;
        } else {
            float2 xv = *(const float2*)xr;
            float2 o;
            o.x = di * acc[0] + di2 * xv.x;
            o.y = di * acc[1] + di2 * xv.y;
            *(float2*)zr = o;
        }
    }
}

// ---------------------------------------------------------------------------
// GEMM: h = z @ W + bias. Block = 32 rows x 256 cols, 256 threads.
// Register tile 8 rows x 4 cols per thread: thread t owns cols (t&63)+64j
// (coalesced W loads & C stores) and rows (t>>6)*8..+8.
// Per k-group of 4: 8 broadcast ds_read_b128 + 16 coalesced W loads + 128 FMA
// (R6 profile showed the old 1-col scheme was LDS-pipe-bound: 32 ds/k-group).
template <int K>
__global__ __launch_bounds__(256) void gcn_gemm_k(
    const float* __restrict__ z, const float* __restrict__ W,
    const float* __restrict__ bias, float* __restrict__ hout, int n) {
    constexpr int BM = 32;
    __shared__ float zs[BM][K];
    const int t  = threadIdx.x;
    const int r0 = blockIdx.x * BM;
    const int jc = t & 63;        // base col
    const int rg = (t >> 6) * 8;  // base row within tile

    // stage z tile
    constexpr int NV = BM * K / 4;  // float4 elements
    for (int v = t; v < NV; v += 256) {
        int m   = v / (K / 4);
        int c   = (v % (K / 4)) * 4;
        int row = r0 + m;
        if (row < n) *(float4*)&zs[m][c] = *(const float4*)(z + (size_t)row * K + c);
        else         *(float4*)&zs[m][c] = make_float4(0.f, 0.f, 0.f, 0.f);
    }
    __syncthreads();

    float acc[8][4];
#pragma unroll
    for (int j = 0; j < 4; j++) {
        float bv = bias[jc + 64 * j];
#pragma unroll
        for (int m = 0; m < 8; m++) acc[m][j] = bv;
    }

    for (int k = 0; k < K; k += 4) {
        float w[4][4];  // [kk][j] — all indices compile-time (fully unrolled)
#pragma unroll
        for (int kk = 0; kk < 4; kk++)
#pragma unroll
            for (int j = 0; j < 4; j++)
                w[kk][j] = W[(size_t)(k + kk) * HDIM + jc + 64 * j];
#pragma unroll
        for (int m = 0; m < 8; m++) {
            float4 z4 = *(const float4*)&zs[rg + m][k];  // broadcast within wave
#pragma unroll
            for (int j = 0; j < 4; j++) {
                acc[m][j] += z4.x * w[0][j] + z4.y * w[1][j]
                           + z4.z * w[2][j] + z4.w * w[3][j];
            }
        }
    }

#pragma unroll
    for (int m = 0; m < 8; m++) {
        int row = r0 + rg + m;
        if (row < n) {
#pragma unroll
            for (int j = 0; j < 4; j++)
                hout[(size_t)row * HDIM + jc + 64 * j] = acc[m][j];
        }
    }
}

// ---------------------------------------------------------------------------
// per-graph sum/sumsq, hierarchical: contiguous node slab per block,
// LDS per-graph accumulators (ds_add atomics), few global atomics per block.
__global__ __launch_bounds__(256) void ln_stats_k(
    const float* __restrict__ h, const int* __restrict__ batch,
    float* __restrict__ gsum, float* __restrict__ gsq, int n, int npb) {
    __shared__ float lsum[NGRAPH], lsq[NGRAPH];
    int t = threadIdx.x;
    if (t < NGRAPH) { lsum[t] = 0.0f; lsq[t] = 0.0f; }
    __syncthreads();
    int wv = t >> 6, lane = t & 63;
    int i0 = blockIdx.x * npb;
    int i1 = i0 + npb; if (i1 > n) i1 = n;
    for (int i = i0 + wv; i < i1; i += 4) {
        float4 v = *(const float4*)(h + (size_t)i * HDIM + lane * 4);
        float s = v.x + v.y + v.z + v.w;
        float q = v.x * v.x + v.y * v.y + v.z * v.z + v.w * v.w;
        for (int o = 32; o; o >>= 1) {
            s += __shfl_down(s, o);
            q += __shfl_down(q, o);
        }
        if (lane == 0) {
            int b = batch[i];
            if (b < 0) b = 0; if (b >= NGRAPH) b = NGRAPH - 1;
            atomicAdd(&lsum[b], s);  // LDS atomic (ds_add)
            atomicAdd(&lsq[b], q);
        }
    }
    __syncthreads();
    if (t < NGRAPH) {
        float s = lsum[t], q = lsq[t];
        if (s != 0.0f || q != 0.0f) {  // only graphs this slab touched
            unsafeAtomicAdd(&gsum[t], s);
            unsafeAtomicAdd(&gsq[t], q);
        }
    }
}

// mean / rstd per graph (counts derived from last_idx of sorted batch)
__global__ void ln_fin_k(const float* __restrict__ gsum, const float* __restrict__ gsq,
                         const int* __restrict__ lastidx, float* __restrict__ mean,
                         float* __restrict__ rstd, int n) {
    int g = threadIdx.x;
    if (g >= NGRAPH) return;
    int last = lastidx[g];
    if (last < 0) last = 0; if (last >= n) last = n - 1;
    int prev = g ? lastidx[g - 1] : -1;
    if (prev < -1) prev = -1; if (prev >= n) prev = n - 1;
    float cnt = (float)(last - prev);
    if (cnt < 1.0f) cnt = 1.0f;
    float denom = cnt * (float)HDIM;
    float m = gsum[g] / denom;
    float v = gsq[g] / denom - m * m;
    if (v < 0.0f) v = 0.0f;
    mean[g] = m;
    rstd[g] = 1.0f / sqrtf(v + 1e-5f);
}

// in-place: h = tanh((h - mean)*rstd*w + b)
__global__ void ln_tanh_k(float* __restrict__ h, const int* __restrict__ batch,
                          const float* __restrict__ mean, const float* __restrict__ rstd,
                          const float* __restrict__ w, const float* __restrict__ b, int n) {
    long gid = (long)blockIdx.x * blockDim.x + threadIdx.x;
    long total = (long)n * 64;
    if (gid >= total) return;
    int i  = (int)(gid >> 6);
    int c  = (int)(gid & 63) * 4;
    int bg = batch[i];
    if (bg < 0) bg = 0; if (bg >= NGRAPH) bg = NGRAPH - 1;
    float m = mean[bg], r = rstd[bg];
    float4 v  = *(const float4*)(h + (size_t)i * HDIM + c);
    float4 w4 = *(const float4*)(w + c);
    float4 b4 = *(const float4*)(b + c);
    v.x = tanhf((v.x - m) * r * w4.x + b4.x);
    v.y = tanhf((v.y - m) * r * w4.y + b4.y);
    v.z = tanhf((v.z - m) * r * w4.z + b4.z);
    v.w = tanhf((v.w - m) * r * w4.w + b4.w);
    *(float4*)(h + (size_t)i * HDIM + c) = v;
}

// gather the 64 last-node rows of a layer output into xjk[l]
__global__ void extract_rows_k(const float* __restrict__ x, const int* __restrict__ lastidx,
                               float* __restrict__ out, int n) {
    int g = blockIdx.x, c = threadIdx.x;
    int r = lastidx[g];
    if (r < 0) r = 0; if (r >= n) r = n - 1;
    out[(size_t)g * HDIM + c] = x[(size_t)r * HDIM + c];
}

// ---------------------------------------------------------------------------
// head: JK-cat [768] @ jk_w + jk_b -> tanh(fc1) -> fc2, one block per graph
__global__ __launch_bounds__(256) void final_mlp_k(
    const float* __restrict__ xjk,  // [3][64][256]
    const float* __restrict__ jk_w, const float* __restrict__ jk_b,
    const float* __restrict__ fc1_w, const float* __restrict__ fc1_b,
    const float* __restrict__ fc2_w, const float* __restrict__ fc2_b,
    float* __restrict__ out) {
    __shared__ float vec[3 * HDIM];
    __shared__ float h1[HDIM];
    __shared__ float h2[128];
    int g = blockIdx.x, t = threadIdx.x;
    vec[t]            = xjk[(size_t)0 * NGRAPH * HDIM + (size_t)g * HDIM + t];
    vec[HDIM + t]     = xjk[(size_t)1 * NGRAPH * HDIM + (size_t)g * HDIM + t];
    vec[2 * HDIM + t] = xjk[(size_t)2 * NGRAPH * HDIM + (size_t)g * HDIM + t];
    __syncthreads();
    float a = jk_b[t];
    for (int k = 0; k < 3 * HDIM; k++) a += vec[k] * jk_w[(size_t)k * HDIM + t];
    h1[t] = a;
    __syncthreads();
    if (t < 128) {
        float a2 = fc1_b[t];
        for (int k = 0; k < HDIM; k++) a2 += h1[k] * fc1_w[(size_t)k * 128 + t];
        h2[t] = tanhf(a2);
    }
    __syncthreads();
    if (t < 64) {
        float a3 = h2[t] * fc2_w[t] + h2[t + 64] * fc2_w[t + 64];
        for (int o = 32; o; o >>= 1) a3 += __shfl_down(a3, o);
        if (t == 0) out[g] = a3 + fc2_b[0];
    }
}

// ---------------------------------------------------------------------------
extern "C" void kernel_launch(void* const* d_in, const int* in_sizes, int n_in,
                              void* d_out, int out_size, void* d_ws, size_t ws_size,
                              hipStream_t stream) {
    const float* x    = (const float*)d_in[0];
    const float* W1   = (const float*)d_in[1];
    const float* b1   = (const float*)d_in[2];
    const float* ln1w = (const float*)d_in[3];
    const float* ln1b = (const float*)d_in[4];
    const float* W2   = (const float*)d_in[5];
    const float* b2   = (const float*)d_in[6];
    const float* ln2w = (const float*)d_in[7];
    const float* ln2b = (const float*)d_in[8];
    const float* W3   = (const float*)d_in[9];
    const float* b3   = (const float*)d_in[10];
    const float* ln3w = (const float*)d_in[11];
    const float* ln3b = (const float*)d_in[12];
    const float* jkw  = (const float*)d_in[13];
    const float* jkb  = (const float*)d_in[14];
    const float* fc1w = (const float*)d_in[15];
    const float* fc1b = (const float*)d_in[16];
    const float* fc2w = (const float*)d_in[17];
    const float* fc2b = (const float*)d_in[18];
    const int*  eidx  = (const int*)d_in[19];
    const int*  batch = (const int*)d_in[20];

    const int E = in_sizes[19] / 2;
    const int n = in_sizes[20];

    const int* src = eidx;
    const int* dst = eidx + E;

    // workspace carve-up (~213 MB):
    char* base = (char*)d_ws;
    size_t o = 0;
    auto alloc = [&](size_t bytes) { void* p = base + o; o += (bytes + 255) & ~(size_t)255; return p; };
    float* bufZ = (float*)alloc((size_t)n * HDIM * 4);
    float* bufH = (float*)alloc((size_t)n * HDIM * 4);
    int*   csr  = (int*)alloc((size_t)E * 4);
    int*   rs   = (int*)alloc((size_t)(n + 1) * 4);
    int*   cur  = (int*)alloc((size_t)n * 4);
    int*   degi = (int*)alloc((size_t)n * 4);
    float* dinv = (float*)alloc((size_t)n * 4);
    int*   part = (int*)alloc(1024 * 4);
    float* xjk  = (float*)alloc((size_t)3 * NGRAPH * HDIM * 4);
    int*   lidx = (int*)alloc(NGRAPH * 4);
    float* gsum = (float*)alloc(NGRAPH * 4);
    float* gsq  = (float*)alloc(NGRAPH * 4);
    float* mean = (float*)alloc(NGRAPH * 4);
    float* rstd = (float*)alloc(NGRAPH * 4);
    (void)ws_size;

    float* out = (float*)d_out;
    const int GB = (n + 31) / 32;                       // gemm blocks
    const int NB = (n + SCAN_CHUNK - 1) / SCAN_CHUNK;   // scan blocks (49)
    const int AB = 2048;                                // agg blocks (8192 waves = 32/CU)
    const int SB = 1024;                                // ln_stats blocks
    const int NPB = (n + SB - 1) / SB;                  // nodes per stats block (~98)

    // --- CSR build + degrees + last-node indices (once per call) ---
    hipMemsetAsync(degi, 0, (size_t)n * 4, stream);
    hipMemsetAsync(lidx, 0, NGRAPH * 4, stream);
    deg_count_k<<<(E + 255) / 256, 256, 0, stream>>>(dst, degi, E, n);
    dinv_k<<<(n + 255) / 256, 256, 0, stream>>>(degi, dinv, n);
    last_idx_k<<<(n + 255) / 256, 256, 0, stream>>>(batch, lidx, n);
    scan1_k<<<NB, 256, 0, stream>>>(degi, part, n);
    scan2_k<<<1, 1024, 0, stream>>>(part, NB, rs, n);
    scan3_k<<<NB, 256, 0, stream>>>(degi, part, rs, cur, n);
    scatter_k<<<(E + 255) / 256, 256, 0, stream>>>(src, dst, cur, csr, E, n);

    // ---------------- layer 1 (K = 128) ----------------
    agg_csr_k<128><<<AB, 256, 0, stream>>>(rs, csr, x, dinv, bufZ, n);
    gcn_gemm_k<128><<<GB, 256, 0, stream>>>(bufZ, W1, b1, bufH, n);
    hipMemsetAsync(gsum, 0, 2 * NGRAPH * 4, stream);  // gsum+gsq contiguous
    ln_stats_k<<<SB, 256, 0, stream>>>(bufH, batch, gsum, gsq, n, NPB);
    ln_fin_k<<<1, 64, 0, stream>>>(gsum, gsq, lidx, mean, rstd, n);
    ln_tanh_k<<<(int)(((long)n * 64 + 255) / 256), 256, 0, stream>>>(bufH, batch, mean, rstd, ln1w, ln1b, n);
    extract_rows_k<<<NGRAPH, 256, 0, stream>>>(bufH, lidx, xjk + 0 * NGRAPH * HDIM, n);

    // ---------------- layer 2 ----------------
    agg_csr_k<256><<<AB, 256, 0, stream>>>(rs, csr, bufH, dinv, bufZ, n);
    gcn_gemm_k<256><<<GB, 256, 0, stream>>>(bufZ, W2, b2, bufH, n);
    hipMemsetAsync(gsum, 0, 2 * NGRAPH * 4, stream);
    ln_stats_k<<<SB, 256, 0, stream>>>(bufH, batch, gsum, gsq, n, NPB);
    ln_fin_k<<<1, 64, 0, stream>>>(gsum, gsq, lidx, mean, rstd, n);
    ln_tanh_k<<<(int)(((long)n * 64 + 255) / 256), 256, 0, stream>>>(bufH, batch, mean, rstd, ln2w, ln2b, n);
    extract_rows_k<<<NGRAPH, 256, 0, stream>>>(bufH, lidx, xjk + 1 * NGRAPH * HDIM, n);

    // ---------------- layer 3 ----------------
    agg_csr_k<256><<<AB, 256, 0, stream>>>(rs, csr, bufH, dinv, bufZ, n);
    gcn_gemm_k<256><<<GB, 256, 0, stream>>>(bufZ, W3, b3, bufH, n);
    hipMemsetAsync(gsum, 0, 2 * NGRAPH * 4, stream);
    ln_stats_k<<<SB, 256, 0, stream>>>(bufH, batch, gsum, gsq, n, NPB);
    ln_fin_k<<<1, 64, 0, stream>>>(gsum, gsq, lidx, mean, rstd, n);
    ln_tanh_k<<<(int)(((long)n * 64 + 255) / 256), 256, 0, stream>>>(bufH, batch, mean, rstd, ln3w, ln3b, n);
    extract_rows_k<<<NGRAPH, 256, 0, stream>>>(bufH, lidx, xjk + 2 * NGRAPH * HDIM, n);

    // ---------------- head (64 nodes only) ----------------
    final_mlp_k<<<NGRAPH, 256, 0, stream>>>(xjk, jkw, jkb, fc1w, fc1b, fc2w, fc2b, out);
}

// Round 10
// 1420.195 us; speedup vs baseline: 2.9632x; 1.2107x over previous
//
#include <hip/hip_runtime.h>
#include <hip/hip_bf16.h>
#include <hip/hip_fp16.h>
#include <math.h>

// Problem constants: N=100000 nodes, E=1600000 edges, D=128, H=256, B=64.
// R5: 4208us baseline. R6: 1981us (ln_stats LDS fix). R7: 1719us (gemm reg-tile).
// R8/R9: fp16 gather tables (never benched - infra timeouts). R10: resubmit.
// Theory: agg_csr gather-BW-bound (864MB fetch, 5.9TB/s effective) -> halve bytes.
#define HDIM 256
#define NGRAPH 64
#define SCAN_CHUNK 2048  // 256 threads x 8 elems

__device__ inline __half2 u2h2(unsigned u) { return *reinterpret_cast<__half2*>(&u); }
__device__ inline unsigned h22u(__half2 h) { return *reinterpret_cast<unsigned*>(&h); }

// ---------------------------------------------------------------------------
// in-degree count (int atomics)
__global__ void deg_count_k(const int* __restrict__ dst, int* __restrict__ deg, int E, int n) {
    int i = blockIdx.x * blockDim.x + threadIdx.x;
    if (i < E) {
        int d = dst[i];
        if ((unsigned)d < (unsigned)n) atomicAdd(&deg[d], 1);
    }
}

// dinv[i] = 1/sqrt(in_deg[i] + 1)
__global__ void dinv_k(const int* __restrict__ deg, float* __restrict__ dinv, int n) {
    int i = blockIdx.x * blockDim.x + threadIdx.x;
    if (i < n) dinv[i] = 1.0f / sqrtf((float)deg[i] + 1.0f);
}

// last node index of each (sorted, consecutive) graph id
__global__ void last_idx_k(const int* __restrict__ batch, int* __restrict__ lastidx, int n) {
    int i = blockIdx.x * blockDim.x + threadIdx.x;
    if (i < n) {
        int b = batch[i];
        if ((i == n - 1 || batch[i + 1] != b) && b >= 0 && b < NGRAPH) lastidx[b] = i;
    }
}

// convert fp32 -> fp16 table (4 elems/thread)
__global__ void cvt_x_k(const float* __restrict__ x, __half* __restrict__ xh, long n4) {
    long i = (long)blockIdx.x * blockDim.x + threadIdx.x;
    if (i < n4) {
        float4 v = *(const float4*)(x + i * 4);
        __half2 p0 = __float22half2_rn(make_float2(v.x, v.y));
        __half2 p1 = __float22half2_rn(make_float2(v.z, v.w));
        uint2 st; st.x = h22u(p0); st.y = h22u(p1);
        *(uint2*)(xh + i * 4) = st;
    }
}

// --------------------------- exclusive prefix scan -------------------------
__global__ __launch_bounds__(256) void scan1_k(const int* __restrict__ deg,
                                               int* __restrict__ partial, int n) {
    __shared__ int sm[256];
    int t = threadIdx.x;
    int base = blockIdx.x * SCAN_CHUNK + t * 8;
    int s = 0;
#pragma unroll
    for (int j = 0; j < 8; j++) { int idx = base + j; if (idx < n) s += deg[idx]; }
    sm[t] = s; __syncthreads();
    for (int o = 128; o; o >>= 1) { if (t < o) sm[t] += sm[t + o]; __syncthreads(); }
    if (t == 0) partial[blockIdx.x] = sm[0];
}

__global__ __launch_bounds__(1024) void scan2_k(int* __restrict__ partial, int nb,
                                                int* __restrict__ rs, int n) {
    __shared__ int sm[1024];
    int t = threadIdx.x;
    int v = (t < nb) ? partial[t] : 0;
    sm[t] = v; __syncthreads();
    for (int o = 1; o < 1024; o <<= 1) {
        int add = (t >= o) ? sm[t - o] : 0;
        __syncthreads();
        sm[t] += add;
        __syncthreads();
    }
    if (t < nb) partial[t] = sm[t] - v;  // exclusive block offset
    if (t == nb - 1) rs[n] = sm[t];      // total edge count
}

__global__ __launch_bounds__(256) void scan3_k(const int* __restrict__ deg,
                                               const int* __restrict__ partial,
                                               int* __restrict__ rs, int* __restrict__ cur, int n) {
    __shared__ int sm[256];
    int t = threadIdx.x;
    int base = blockIdx.x * SCAN_CHUNK + t * 8;
    int loc[8]; int s = 0;
#pragma unroll
    for (int j = 0; j < 8; j++) {
        int idx = base + j;
        loc[j] = (idx < n) ? deg[idx] : 0;
        s += loc[j];
    }
    sm[t] = s; __syncthreads();
    int v = s;
    for (int o = 1; o < 256; o <<= 1) {
        int add = (t >= o) ? sm[t - o] : 0;
        __syncthreads();
        sm[t] += add;
        __syncthreads();
    }
    int run = partial[blockIdx.x] + sm[t] - v;  // exclusive prefix for this thread
#pragma unroll
    for (int j = 0; j < 8; j++) {
        int idx = base + j;
        if (idx < n) { rs[idx] = run; cur[idx] = run; }
        run += loc[j];
    }
}

// scatter edges into CSR buckets (int atomics on cursors, ~E ops total)
__global__ void scatter_k(const int* __restrict__ src, const int* __restrict__ dst,
                          int* __restrict__ cur, int* __restrict__ csr, int E, int n) {
    int e = blockIdx.x * blockDim.x + threadIdx.x;
    if (e < E) {
        int d = dst[e], s = src[e];
        if ((unsigned)d < (unsigned)n && (unsigned)s < (unsigned)n) {
            int pos = atomicAdd(&cur[d], 1);
            csr[pos] = s;
        }
    }
}

// ---------------------------------------------------------------------------
// CSR aggregation, atomic-free, fp16 gather table, fp16 z output.
// z[i] = dinv[i] * sum_{s in in(i)} dinv[s]*x[s]  +  dinv[i]^2 * x[i]
template <int DIM>
__global__ __launch_bounds__(256) void agg_csr_k(
    const int* __restrict__ rs, const int* __restrict__ csr,
    const __half* __restrict__ xin, const float* __restrict__ dinv,
    __half* __restrict__ z, int n) {
    constexpr int VEC = DIM / 64;  // 2 (DIM=128) or 4 (DIM=256)
    int wid  = (blockIdx.x * blockDim.x + threadIdx.x) >> 6;
    int lane = threadIdx.x & 63;
    int nw   = (gridDim.x * blockDim.x) >> 6;
    for (int i = wid; i < n; i += nw) {
        int j0 = rs[i], j1 = rs[i + 1];
        float acc[VEC];
#pragma unroll
        for (int v = 0; v < VEC; v++) acc[v] = 0.0f;

        for (int jb = j0; jb < j1; jb += 64) {
            int m = j1 - jb; if (m > 64) m = 64;
            int   sj = (lane < m) ? csr[jb + lane] : 0;
            float wj = (lane < m) ? dinv[sj] : 0.0f;
#pragma unroll 4
            for (int r = 0; r < m; r++) {
                int   s = __shfl(sj, r);
                float w = __shfl(wj, r);
                const __half* xr = xin + (size_t)s * DIM + lane * VEC;
                if constexpr (VEC == 4) {
                    uint2 u = *(const uint2*)xr;
                    float2 a = __half22float2(u2h2(u.x));
                    float2 b = __half22float2(u2h2(u.y));
                    acc[0] += a.x * w; acc[1] += a.y * w;
                    acc[2] += b.x * w; acc[3] += b.y * w;
                } else {
                    unsigned u = *(const unsigned*)xr;
                    float2 a = __half22float2(u2h2(u));
                    acc[0] += a.x * w; acc[1] += a.y * w;
                }
            }
        }

        float di  = dinv[i];
        float di2 = di * di;
        const __half* xr = xin + (size_t)i * DIM + lane * VEC;
        __half* zr = z + (size_t)i * DIM + lane * VEC;
        if constexpr (VEC == 4) {
            uint2 u = *(const uint2*)xr;
            float2 a = __half22float2(u2h2(u.x));
            float2 b = __half22float2(u2h2(u.y));
            float4 o;
            o.x = di * acc[0] + di2 * a.x;
            o.y = di * acc[1] + di2 * a.y;
            o.z = di * acc[2] + di2 * b.x;
            o.w = di * acc[3] + di2 * b.y;
            __half2 p0 = __float22half2_rn(make_float2(o.x, o.y));
            __half2 p1 = __float22half2_rn(make_float2(o.z, o.w));
            uint2 st; st.x = h22u(p0); st.y = h22u(p1);
            *(uint2*)zr = st;
        } else {
            unsigned u = *(const unsigned*)xr;
            float2 a = __half22float2(u2h2(u));
            float2 o;
            o.x = di * acc[0] + di2 * a.x;
            o.y = di * acc[1] + di2 * a.y;
            *(unsigned*)zr = h22u(__float22half2_rn(o));
        }
    }
}

// ---------------------------------------------------------------------------
// GEMM: h = z @ W + bias. Block = 32 rows x 256 cols, 256 threads.
// Register tile 8 rows x 4 cols/thread (R7). z is fp16; converted in staging.
template <int K>
__global__ __launch_bounds__(256) void gcn_gemm_k(
    const __half* __restrict__ z, const float* __restrict__ W,
    const float* __restrict__ bias, float* __restrict__ hout, int n) {
    constexpr int BM = 32;
    __shared__ float zs[BM][K];
    const int t  = threadIdx.x;
    const int r0 = blockIdx.x * BM;
    const int jc = t & 63;        // base col
    const int rg = (t >> 6) * 8;  // base row within tile

    // stage z tile (fp16 -> fp32), 4 elems / thread / iter
    constexpr int NV = BM * K / 4;
    for (int v = t; v < NV; v += 256) {
        int m   = v / (K / 4);
        int c   = (v % (K / 4)) * 4;
        int row = r0 + m;
        if (row < n) {
            uint2 u = *(const uint2*)(z + (size_t)row * K + c);
            float2 a = __half22float2(u2h2(u.x));
            float2 b = __half22float2(u2h2(u.y));
            zs[m][c] = a.x; zs[m][c + 1] = a.y; zs[m][c + 2] = b.x; zs[m][c + 3] = b.y;
        } else {
            *(float4*)&zs[m][c] = make_float4(0.f, 0.f, 0.f, 0.f);
        }
    }
    __syncthreads();

    float acc[8][4];
#pragma unroll
    for (int j = 0; j < 4; j++) {
        float bv = bias[jc + 64 * j];
#pragma unroll
        for (int m = 0; m < 8; m++) acc[m][j] = bv;
    }

    for (int k = 0; k < K; k += 4) {
        float w[4][4];
#pragma unroll
        for (int kk = 0; kk < 4; kk++)
#pragma unroll
            for (int j = 0; j < 4; j++)
                w[kk][j] = W[(size_t)(k + kk) * HDIM + jc + 64 * j];
#pragma unroll
        for (int m = 0; m < 8; m++) {
            float4 z4 = *(const float4*)&zs[rg + m][k];  // broadcast within wave
#pragma unroll
            for (int j = 0; j < 4; j++) {
                acc[m][j] += z4.x * w[0][j] + z4.y * w[1][j]
                           + z4.z * w[2][j] + z4.w * w[3][j];
            }
        }
    }

#pragma unroll
    for (int m = 0; m < 8; m++) {
        int row = r0 + rg + m;
        if (row < n) {
#pragma unroll
            for (int j = 0; j < 4; j++)
                hout[(size_t)row * HDIM + jc + 64 * j] = acc[m][j];
        }
    }
}

// ---------------------------------------------------------------------------
// per-graph sum/sumsq, hierarchical: contiguous node slab per block,
// LDS per-graph accumulators, few global atomics per block. (R6 fix)
__global__ __launch_bounds__(256) void ln_stats_k(
    const float* __restrict__ h, const int* __restrict__ batch,
    float* __restrict__ gsum, float* __restrict__ gsq, int n, int npb) {
    __shared__ float lsum[NGRAPH], lsq[NGRAPH];
    int t = threadIdx.x;
    if (t < NGRAPH) { lsum[t] = 0.0f; lsq[t] = 0.0f; }
    __syncthreads();
    int wv = t >> 6, lane = t & 63;
    int i0 = blockIdx.x * npb;
    int i1 = i0 + npb; if (i1 > n) i1 = n;
    for (int i = i0 + wv; i < i1; i += 4) {
        float4 v = *(const float4*)(h + (size_t)i * HDIM + lane * 4);
        float s = v.x + v.y + v.z + v.w;
        float q = v.x * v.x + v.y * v.y + v.z * v.z + v.w * v.w;
        for (int o = 32; o; o >>= 1) {
            s += __shfl_down(s, o);
            q += __shfl_down(q, o);
        }
        if (lane == 0) {
            int b = batch[i];
            if (b < 0) b = 0; if (b >= NGRAPH) b = NGRAPH - 1;
            atomicAdd(&lsum[b], s);  // LDS atomic
            atomicAdd(&lsq[b], q);
        }
    }
    __syncthreads();
    if (t < NGRAPH) {
        float s = lsum[t], q = lsq[t];
        if (s != 0.0f || q != 0.0f) {
            unsafeAtomicAdd(&gsum[t], s);
            unsafeAtomicAdd(&gsq[t], q);
        }
    }
}

// mean / rstd per graph (counts derived from last_idx of sorted batch)
__global__ void ln_fin_k(const float* __restrict__ gsum, const float* __restrict__ gsq,
                         const int* __restrict__ lastidx, float* __restrict__ mean,
                         float* __restrict__ rstd, int n) {
    int g = threadIdx.x;
    if (g >= NGRAPH) return;
    int last = lastidx[g];
    if (last < 0) last = 0; if (last >= n) last = n - 1;
    int prev = g ? lastidx[g - 1] : -1;
    if (prev < -1) prev = -1; if (prev >= n) prev = n - 1;
    float cnt = (float)(last - prev);
    if (cnt < 1.0f) cnt = 1.0f;
    float denom = cnt * (float)HDIM;
    float m = gsum[g] / denom;
    float v = gsq[g] / denom - m * m;
    if (v < 0.0f) v = 0.0f;
    mean[g] = m;
    rstd[g] = 1.0f / sqrtf(v + 1e-5f);
}

// h16 = tanh((h - mean)*rstd*w + b)  (fp32 in, fp16 out)
__global__ void ln_tanh_k(const float* __restrict__ h, const int* __restrict__ batch,
                          const float* __restrict__ mean, const float* __restrict__ rstd,
                          const float* __restrict__ w, const float* __restrict__ b,
                          __half* __restrict__ h16, int n) {
    long gid = (long)blockIdx.x * blockDim.x + threadIdx.x;
    long total = (long)n * 64;
    if (gid >= total) return;
    int i  = (int)(gid >> 6);
    int c  = (int)(gid & 63) * 4;
    int bg = batch[i];
    if (bg < 0) bg = 0; if (bg >= NGRAPH) bg = NGRAPH - 1;
    float m = mean[bg], r = rstd[bg];
    float4 v  = *(const float4*)(h + (size_t)i * HDIM + c);
    float4 w4 = *(const float4*)(w + c);
    float4 b4 = *(const float4*)(b + c);
    v.x = tanhf((v.x - m) * r * w4.x + b4.x);
    v.y = tanhf((v.y - m) * r * w4.y + b4.y);
    v.z = tanhf((v.z - m) * r * w4.z + b4.z);
    v.w = tanhf((v.w - m) * r * w4.w + b4.w);
    __half2 p0 = __float22half2_rn(make_float2(v.x, v.y));
    __half2 p1 = __float22half2_rn(make_float2(v.z, v.w));
    uint2 st; st.x = h22u(p0); st.y = h22u(p1);
    *(uint2*)(h16 + (size_t)i * HDIM + c) = st;
}

// gather the 64 last-node rows (fp16) of a layer output into xjk (fp32)
__global__ void extract_rows_k(const __half* __restrict__ x, const int* __restrict__ lastidx,
                               float* __restrict__ out, int n) {
    int g = blockIdx.x, c = threadIdx.x;
    int r = lastidx[g];
    if (r < 0) r = 0; if (r >= n) r = n - 1;
    out[(size_t)g * HDIM + c] = __half2float(x[(size_t)r * HDIM + c]);
}

// ---------------------------------------------------------------------------
// head: JK-cat [768] @ jk_w + jk_b -> tanh(fc1) -> fc2, one block per graph
__global__ __launch_bounds__(256) void final_mlp_k(
    const float* __restrict__ xjk,  // [3][64][256]
    const float* __restrict__ jk_w, const float* __restrict__ jk_b,
    const float* __restrict__ fc1_w, const float* __restrict__ fc1_b,
    const float* __restrict__ fc2_w, const float* __restrict__ fc2_b,
    float* __restrict__ out) {
    __shared__ float vec[3 * HDIM];
    __shared__ float h1[HDIM];
    __shared__ float h2[128];
    int g = blockIdx.x, t = threadIdx.x;
    vec[t]            = xjk[(size_t)0 * NGRAPH * HDIM + (size_t)g * HDIM + t];
    vec[HDIM + t]     = xjk[(size_t)1 * NGRAPH * HDIM + (size_t)g * HDIM + t];
    vec[2 * HDIM + t] = xjk[(size_t)2 * NGRAPH * HDIM + (size_t)g * HDIM + t];
    __syncthreads();
    float a = jk_b[t];
    for (int k = 0; k < 3 * HDIM; k++) a += vec[k] * jk_w[(size_t)k * HDIM + t];
    h1[t] = a;
    __syncthreads();
    if (t < 128) {
        float a2 = fc1_b[t];
        for (int k = 0; k < HDIM; k++) a2 += h1[k] * fc1_w[(size_t)k * 128 + t];
        h2[t] = tanhf(a2);
    }
    __syncthreads();
    if (t < 64) {
        float a3 = h2[t] * fc2_w[t] + h2[t + 64] * fc2_w[t + 64];
        for (int o = 32; o; o >>= 1) a3 += __shfl_down(a3, o);
        if (t == 0) out[g] = a3 + fc2_b[0];
    }
}

// ---------------------------------------------------------------------------
extern "C" void kernel_launch(void* const* d_in, const int* in_sizes, int n_in,
                              void* d_out, int out_size, void* d_ws, size_t ws_size,
                              hipStream_t stream) {
    const float* x    = (const float*)d_in[0];
    const float* W1   = (const float*)d_in[1];
    const float* b1   = (const float*)d_in[2];
    const float* ln1w = (const float*)d_in[3];
    const float* ln1b = (const float*)d_in[4];
    const float* W2   = (const float*)d_in[5];
    const float* b2   = (const float*)d_in[6];
    const float* ln2w = (const float*)d_in[7];
    const float* ln2b = (const float*)d_in[8];
    const float* W3   = (const float*)d_in[9];
    const float* b3   = (const float*)d_in[10];
    const float* ln3w = (const float*)d_in[11];
    const float* ln3b = (const float*)d_in[12];
    const float* jkw  = (const float*)d_in[13];
    const float* jkb  = (const float*)d_in[14];
    const float* fc1w = (const float*)d_in[15];
    const float* fc1b = (const float*)d_in[16];
    const float* fc2w = (const float*)d_in[17];
    const float* fc2b = (const float*)d_in[18];
    const int*  eidx  = (const int*)d_in[19];
    const int*  batch = (const int*)d_in[20];

    const int E = in_sizes[19] / 2;
    const int n = in_sizes[20];
    const int D = in_sizes[0] / n;  // 128

    const int* src = eidx;
    const int* dst = eidx + E;

    // workspace carve-up (~160 MB):
    char* base = (char*)d_ws;
    size_t o = 0;
    auto alloc = [&](size_t bytes) { void* p = base + o; o += (bytes + 255) & ~(size_t)255; return p; };
    __half* bufZ = (__half*)alloc((size_t)n * HDIM * 2);   // fp16 z
    float*  bufH = (float*)alloc((size_t)n * HDIM * 4);    // fp32 pre-LN h
    __half* hF   = (__half*)alloc((size_t)n * HDIM * 2);   // fp16 gather table (x16, then h16)
    int*   csr  = (int*)alloc((size_t)E * 4);
    int*   rs   = (int*)alloc((size_t)(n + 1) * 4);
    int*   cur  = (int*)alloc((size_t)n * 4);
    int*   degi = (int*)alloc((size_t)n * 4);
    float* dinv = (float*)alloc((size_t)n * 4);
    int*   part = (int*)alloc(1024 * 4);
    float* xjk  = (float*)alloc((size_t)3 * NGRAPH * HDIM * 4);
    int*   lidx = (int*)alloc(NGRAPH * 4);
    float* gsum = (float*)alloc(NGRAPH * 4);
    float* gsq  = (float*)alloc(NGRAPH * 4);
    float* mean = (float*)alloc(NGRAPH * 4);
    float* rstd = (float*)alloc(NGRAPH * 4);
    (void)ws_size;

    float* out = (float*)d_out;
    const int GB = (n + 31) / 32;                       // gemm blocks
    const int NB = (n + SCAN_CHUNK - 1) / SCAN_CHUNK;   // scan blocks (49)
    const int AB = 2048;                                // agg blocks (8192 waves)
    const int SB = 1024;                                // ln_stats blocks
    const int NPB = (n + SB - 1) / SB;                  // nodes per stats block (~98)

    // --- CSR build + degrees + last-node indices + x->fp16 (once per call) ---
    hipMemsetAsync(degi, 0, (size_t)n * 4, stream);
    hipMemsetAsync(lidx, 0, NGRAPH * 4, stream);
    deg_count_k<<<(E + 255) / 256, 256, 0, stream>>>(dst, degi, E, n);
    dinv_k<<<(n + 255) / 256, 256, 0, stream>>>(degi, dinv, n);
    last_idx_k<<<(n + 255) / 256, 256, 0, stream>>>(batch, lidx, n);
    scan1_k<<<NB, 256, 0, stream>>>(degi, part, n);
    scan2_k<<<1, 1024, 0, stream>>>(part, NB, rs, n);
    scan3_k<<<NB, 256, 0, stream>>>(degi, part, rs, cur, n);
    scatter_k<<<(E + 255) / 256, 256, 0, stream>>>(src, dst, cur, csr, E, n);
    long n4 = (long)n * D / 4;
    cvt_x_k<<<(int)((n4 + 255) / 256), 256, 0, stream>>>(x, hF, n4);  // hF holds x16 [n][128]

    // ---------------- layer 1 (K = 128) ----------------
    agg_csr_k<128><<<AB, 256, 0, stream>>>(rs, csr, hF, dinv, bufZ, n);
    gcn_gemm_k<128><<<GB, 256, 0, stream>>>(bufZ, W1, b1, bufH, n);
    hipMemsetAsync(gsum, 0, 2 * NGRAPH * 4, stream);  // gsum+gsq contiguous
    ln_stats_k<<<SB, 256, 0, stream>>>(bufH, batch, gsum, gsq, n, NPB);
    ln_fin_k<<<1, 64, 0, stream>>>(gsum, gsq, lidx, mean, rstd, n);
    ln_tanh_k<<<(int)(((long)n * 64 + 255) / 256), 256, 0, stream>>>(bufH, batch, mean, rstd, ln1w, ln1b, hF, n);  // hF now h16 [n][256]
    extract_rows_k<<<NGRAPH, 256, 0, stream>>>(hF, lidx, xjk + 0 * NGRAPH * HDIM, n);

    // ---------------- layer 2 ----------------
    agg_csr_k<256><<<AB, 256, 0, stream>>>(rs, csr, hF, dinv, bufZ, n);
    gcn_gemm_k<256><<<GB, 256, 0, stream>>>(bufZ, W2, b2, bufH, n);
    hipMemsetAsync(gsum, 0, 2 * NGRAPH * 4, stream);
    ln_stats_k<<<SB, 256, 0, stream>>>(bufH, batch, gsum, gsq, n, NPB);
    ln_fin_k<<<1, 64, 0, stream>>>(gsum, gsq, lidx, mean, rstd, n);
    ln_tanh_k<<<(int)(((long)n * 64 + 255) / 256), 256, 0, stream>>>(bufH, batch, mean, rstd, ln2w, ln2b, hF, n);
    extract_rows_k<<<NGRAPH, 256, 0, stream>>>(hF, lidx, xjk + 1 * NGRAPH * HDIM, n);

    // ---------------- layer 3 ----------------
    agg_csr_k<256><<<AB, 256, 0, stream>>>(rs, csr, hF, dinv, bufZ, n);
    gcn_gemm_k<256><<<GB, 256, 0, stream>>>(bufZ, W3, b3, bufH, n);
    hipMemsetAsync(gsum, 0, 2 * NGRAPH * 4, stream);
    ln_stats_k<<<SB, 256, 0, stream>>>(bufH, batch, gsum, gsq, n, NPB);
    ln_fin_k<<<1, 64, 0, stream>>>(gsum, gsq, lidx, mean, rstd, n);
    ln_tanh_k<<<(int)(((long)n * 64 + 255) / 256), 256, 0, stream>>>(bufH, batch, mean, rstd, ln3w, ln3b, hF, n);
    extract_rows_k<<<NGRAPH, 256, 0, stream>>>(hF, lidx, xjk + 2 * NGRAPH * HDIM, n);

    // ---------------- head (64 nodes only) ----------------
    final_mlp_k<<<NGRAPH, 256, 0, stream>>>(xjk, jkw, jkb, fc1w, fc1b, fc2w, fc2b, out);
}

// Round 12
// 1134.298 us; speedup vs baseline: 3.7100x; 1.2520x over previous
//
#include <hip/hip_runtime.h>
#include <hip/hip_bf16.h>
#include <hip/hip_fp16.h>
#include <math.h>

// Problem constants: N=100000 nodes, E=1600000 edges, D=128, H=256, B=64.
// R5: 4208us. R6: 1981us (ln_stats LDS fix). R7: 1719us (gemm reg-tile).
// R10: 1420us (fp16 gather tables, absmax 0.00195).
// R11/R12: MFMA f16 GEMM (mfma_f32_16x16x32_f16), W pre-transposed fp16.
// R11 hit infra timeout; R12 is an identical resubmit.
#define HDIM 256
#define NGRAPH 64
#define SCAN_CHUNK 2048  // 256 threads x 8 elems

__device__ inline __half2 u2h2(unsigned u) { return *reinterpret_cast<__half2*>(&u); }
__device__ inline unsigned h22u(__half2 h) { return *reinterpret_cast<unsigned*>(&h); }

typedef _Float16 f16x8 __attribute__((ext_vector_type(8)));
typedef float    f32x4 __attribute__((ext_vector_type(4)));

// ---------------------------------------------------------------------------
// in-degree count (int atomics)
__global__ void deg_count_k(const int* __restrict__ dst, int* __restrict__ deg, int E, int n) {
    int i = blockIdx.x * blockDim.x + threadIdx.x;
    if (i < E) {
        int d = dst[i];
        if ((unsigned)d < (unsigned)n) atomicAdd(&deg[d], 1);
    }
}

// dinv[i] = 1/sqrt(in_deg[i] + 1)
__global__ void dinv_k(const int* __restrict__ deg, float* __restrict__ dinv, int n) {
    int i = blockIdx.x * blockDim.x + threadIdx.x;
    if (i < n) dinv[i] = 1.0f / sqrtf((float)deg[i] + 1.0f);
}

// last node index of each (sorted, consecutive) graph id
__global__ void last_idx_k(const int* __restrict__ batch, int* __restrict__ lastidx, int n) {
    int i = blockIdx.x * blockDim.x + threadIdx.x;
    if (i < n) {
        int b = batch[i];
        if ((i == n - 1 || batch[i + 1] != b) && b >= 0 && b < NGRAPH) lastidx[b] = i;
    }
}

// convert fp32 -> fp16 table (4 elems/thread)
__global__ void cvt_x_k(const float* __restrict__ x, __half* __restrict__ xh, long n4) {
    long i = (long)blockIdx.x * blockDim.x + threadIdx.x;
    if (i < n4) {
        float4 v = *(const float4*)(x + i * 4);
        __half2 p0 = __float22half2_rn(make_float2(v.x, v.y));
        __half2 p1 = __float22half2_rn(make_float2(v.z, v.w));
        uint2 st; st.x = h22u(p0); st.y = h22u(p1);
        *(uint2*)(xh + i * 4) = st;
    }
}

// W [K][256] fp32 -> Wt [256][K] fp16 (coalesced read, scattered 2B write; tiny)
__global__ void cvt_w_k(const float* __restrict__ W, __half* __restrict__ Wt, int K) {
    int idx = blockIdx.x * 256 + threadIdx.x;
    int k = idx >> 8, c = idx & 255;
    if (k < K) Wt[(size_t)c * K + k] = __float2half(W[(size_t)k * HDIM + c]);
}

// --------------------------- exclusive prefix scan -------------------------
__global__ __launch_bounds__(256) void scan1_k(const int* __restrict__ deg,
                                               int* __restrict__ partial, int n) {
    __shared__ int sm[256];
    int t = threadIdx.x;
    int base = blockIdx.x * SCAN_CHUNK + t * 8;
    int s = 0;
#pragma unroll
    for (int j = 0; j < 8; j++) { int idx = base + j; if (idx < n) s += deg[idx]; }
    sm[t] = s; __syncthreads();
    for (int o = 128; o; o >>= 1) { if (t < o) sm[t] += sm[t + o]; __syncthreads(); }
    if (t == 0) partial[blockIdx.x] = sm[0];
}

__global__ __launch_bounds__(1024) void scan2_k(int* __restrict__ partial, int nb,
                                                int* __restrict__ rs, int n) {
    __shared__ int sm[1024];
    int t = threadIdx.x;
    int v = (t < nb) ? partial[t] : 0;
    sm[t] = v; __syncthreads();
    for (int o = 1; o < 1024; o <<= 1) {
        int add = (t >= o) ? sm[t - o] : 0;
        __syncthreads();
        sm[t] += add;
        __syncthreads();
    }
    if (t < nb) partial[t] = sm[t] - v;  // exclusive block offset
    if (t == nb - 1) rs[n] = sm[t];      // total edge count
}

__global__ __launch_bounds__(256) void scan3_k(const int* __restrict__ deg,
                                               const int* __restrict__ partial,
                                               int* __restrict__ rs, int* __restrict__ cur, int n) {
    __shared__ int sm[256];
    int t = threadIdx.x;
    int base = blockIdx.x * SCAN_CHUNK + t * 8;
    int loc[8]; int s = 0;
#pragma unroll
    for (int j = 0; j < 8; j++) {
        int idx = base + j;
        loc[j] = (idx < n) ? deg[idx] : 0;
        s += loc[j];
    }
    sm[t] = s; __syncthreads();
    int v = s;
    for (int o = 1; o < 256; o <<= 1) {
        int add = (t >= o) ? sm[t - o] : 0;
        __syncthreads();
        sm[t] += add;
        __syncthreads();
    }
    int run = partial[blockIdx.x] + sm[t] - v;  // exclusive prefix for this thread
#pragma unroll
    for (int j = 0; j < 8; j++) {
        int idx = base + j;
        if (idx < n) { rs[idx] = run; cur[idx] = run; }
        run += loc[j];
    }
}

// scatter edges into CSR buckets (int atomics on cursors, ~E ops total)
__global__ void scatter_k(const int* __restrict__ src, const int* __restrict__ dst,
                          int* __restrict__ cur, int* __restrict__ csr, int E, int n) {
    int e = blockIdx.x * blockDim.x + threadIdx.x;
    if (e < E) {
        int d = dst[e], s = src[e];
        if ((unsigned)d < (unsigned)n && (unsigned)s < (unsigned)n) {
            int pos = atomicAdd(&cur[d], 1);
            csr[pos] = s;
        }
    }
}

// ---------------------------------------------------------------------------
// CSR aggregation, atomic-free, fp16 gather table, fp16 z output. (R10)
template <int DIM>
__global__ __launch_bounds__(256) void agg_csr_k(
    const int* __restrict__ rs, const int* __restrict__ csr,
    const __half* __restrict__ xin, const float* __restrict__ dinv,
    __half* __restrict__ z, int n) {
    constexpr int VEC = DIM / 64;  // 2 (DIM=128) or 4 (DIM=256)
    int wid  = (blockIdx.x * blockDim.x + threadIdx.x) >> 6;
    int lane = threadIdx.x & 63;
    int nw   = (gridDim.x * blockDim.x) >> 6;
    for (int i = wid; i < n; i += nw) {
        int j0 = rs[i], j1 = rs[i + 1];
        float acc[VEC];
#pragma unroll
        for (int v = 0; v < VEC; v++) acc[v] = 0.0f;

        for (int jb = j0; jb < j1; jb += 64) {
            int m = j1 - jb; if (m > 64) m = 64;
            int   sj = (lane < m) ? csr[jb + lane] : 0;
            float wj = (lane < m) ? dinv[sj] : 0.0f;
#pragma unroll 4
            for (int r = 0; r < m; r++) {
                int   s = __shfl(sj, r);
                float w = __shfl(wj, r);
                const __half* xr = xin + (size_t)s * DIM + lane * VEC;
                if constexpr (VEC == 4) {
                    uint2 u = *(const uint2*)xr;
                    float2 a = __half22float2(u2h2(u.x));
                    float2 b = __half22float2(u2h2(u.y));
                    acc[0] += a.x * w; acc[1] += a.y * w;
                    acc[2] += b.x * w; acc[3] += b.y * w;
                } else {
                    unsigned u = *(const unsigned*)xr;
                    float2 a = __half22float2(u2h2(u));
                    acc[0] += a.x * w; acc[1] += a.y * w;
                }
            }
        }

        float di  = dinv[i];
        float di2 = di * di;
        const __half* xr = xin + (size_t)i * DIM + lane * VEC;
        __half* zr = z + (size_t)i * DIM + lane * VEC;
        if constexpr (VEC == 4) {
            uint2 u = *(const uint2*)xr;
            float2 a = __half22float2(u2h2(u.x));
            float2 b = __half22float2(u2h2(u.y));
            float4 o;
            o.x = di * acc[0] + di2 * a.x;
            o.y = di * acc[1] + di2 * a.y;
            o.z = di * acc[2] + di2 * b.x;
            o.w = di * acc[3] + di2 * b.y;
            __half2 p0 = __float22half2_rn(make_float2(o.x, o.y));
            __half2 p1 = __float22half2_rn(make_float2(o.z, o.w));
            uint2 st; st.x = h22u(p0); st.y = h22u(p1);
            *(uint2*)zr = st;
        } else {
            unsigned u = *(const unsigned*)xr;
            float2 a = __half22float2(u2h2(u));
            float2 o;
            o.x = di * acc[0] + di2 * a.x;
            o.y = di * acc[1] + di2 * a.y;
            *(unsigned*)zr = h22u(__float22half2_rn(o));
        }
    }
}

// ---------------------------------------------------------------------------
// MFMA GEMM: h = z @ W + bias, fp16 inputs, fp32 accumulate/output.
// Block = 32 rows x 256 cols, 4 waves; wave w owns cols w*64..w*64+63.
// Per wave: 2 row-groups x 4 col-groups of 16x16 tiles, K-loop step 32.
// Fragment layout (m89/LabNotes, 16x16x32): A lane l -> row l&15,
// k=(l>>4)*8+j (8 contiguous fp16 -> direct 16B load from row-major z);
// B lane l -> col l&15, same k (contiguous in Wt[c][k]); D lane l ->
// row (l>>4)*4+i, col l&15. acc init = bias[col] (all 4 regs share col).
template <int K>
__global__ __launch_bounds__(256) void gcn_gemm_k(
    const __half* __restrict__ z, const __half* __restrict__ Wt,
    const float* __restrict__ bias, float* __restrict__ hout, int n) {
    const int t   = threadIdx.x;
    const int wv  = t >> 6;
    const int l   = t & 63;
    const int l15 = l & 15;
    const int lhi = l >> 4;  // 0..3
    const int r0  = blockIdx.x * 32;
    const int c0  = wv * 64;

    f32x4 acc[2][4];
#pragma unroll
    for (int cg = 0; cg < 4; cg++) {
        float bv = bias[c0 + cg * 16 + l15];
        f32x4 b4 = {bv, bv, bv, bv};
        acc[0][cg] = b4;
        acc[1][cg] = b4;
    }

    int ra = r0 + l15;      if (ra >= n) ra = n - 1;  // clamped (stores guarded)
    int rb = r0 + 16 + l15; if (rb >= n) rb = n - 1;
    const __half* za = z + (size_t)ra * K + lhi * 8;
    const __half* zb = z + (size_t)rb * K + lhi * 8;
    const __half* wp0 = Wt + (size_t)(c0 + 0 * 16 + l15) * K + lhi * 8;
    const __half* wp1 = Wt + (size_t)(c0 + 1 * 16 + l15) * K + lhi * 8;
    const __half* wp2 = Wt + (size_t)(c0 + 2 * 16 + l15) * K + lhi * 8;
    const __half* wp3 = Wt + (size_t)(c0 + 3 * 16 + l15) * K + lhi * 8;

#pragma unroll
    for (int ks = 0; ks < K; ks += 32) {
        f16x8 a0 = *(const f16x8*)(za + ks);
        f16x8 a1 = *(const f16x8*)(zb + ks);
        f16x8 b0 = *(const f16x8*)(wp0 + ks);
        f16x8 b1 = *(const f16x8*)(wp1 + ks);
        f16x8 b2 = *(const f16x8*)(wp2 + ks);
        f16x8 b3 = *(const f16x8*)(wp3 + ks);
        acc[0][0] = __builtin_amdgcn_mfma_f32_16x16x32_f16(a0, b0, acc[0][0], 0, 0, 0);
        acc[1][0] = __builtin_amdgcn_mfma_f32_16x16x32_f16(a1, b0, acc[1][0], 0, 0, 0);
        acc[0][1] = __builtin_amdgcn_mfma_f32_16x16x32_f16(a0, b1, acc[0][1], 0, 0, 0);
        acc[1][1] = __builtin_amdgcn_mfma_f32_16x16x32_f16(a1, b1, acc[1][1], 0, 0, 0);
        acc[0][2] = __builtin_amdgcn_mfma_f32_16x16x32_f16(a0, b2, acc[0][2], 0, 0, 0);
        acc[1][2] = __builtin_amdgcn_mfma_f32_16x16x32_f16(a1, b2, acc[1][2], 0, 0, 0);
        acc[0][3] = __builtin_amdgcn_mfma_f32_16x16x32_f16(a0, b3, acc[0][3], 0, 0, 0);
        acc[1][3] = __builtin_amdgcn_mfma_f32_16x16x32_f16(a1, b3, acc[1][3], 0, 0, 0);
    }

#pragma unroll
    for (int rg = 0; rg < 2; rg++) {
#pragma unroll
        for (int i = 0; i < 4; i++) {
            int r = r0 + rg * 16 + lhi * 4 + i;
            if (r < n) {
                float* hp = hout + (size_t)r * HDIM + c0 + l15;
#pragma unroll
                for (int cg = 0; cg < 4; cg++)
                    hp[cg * 16] = acc[rg][cg][i];
            }
        }
    }
}

// ---------------------------------------------------------------------------
// per-graph sum/sumsq, hierarchical: contiguous node slab per block,
// LDS per-graph accumulators, few global atomics per block. (R6 fix)
__global__ __launch_bounds__(256) void ln_stats_k(
    const float* __restrict__ h, const int* __restrict__ batch,
    float* __restrict__ gsum, float* __restrict__ gsq, int n, int npb) {
    __shared__ float lsum[NGRAPH], lsq[NGRAPH];
    int t = threadIdx.x;
    if (t < NGRAPH) { lsum[t] = 0.0f; lsq[t] = 0.0f; }
    __syncthreads();
    int wv = t >> 6, lane = t & 63;
    int i0 = blockIdx.x * npb;
    int i1 = i0 + npb; if (i1 > n) i1 = n;
    for (int i = i0 + wv; i < i1; i += 4) {
        float4 v = *(const float4*)(h + (size_t)i * HDIM + lane * 4);
        float s = v.x + v.y + v.z + v.w;
        float q = v.x * v.x + v.y * v.y + v.z * v.z + v.w * v.w;
        for (int o = 32; o; o >>= 1) {
            s += __shfl_down(s, o);
            q += __shfl_down(q, o);
        }
        if (lane == 0) {
            int b = batch[i];
            if (b < 0) b = 0; if (b >= NGRAPH) b = NGRAPH - 1;
            atomicAdd(&lsum[b], s);  // LDS atomic
            atomicAdd(&lsq[b], q);
        }
    }
    __syncthreads();
    if (t < NGRAPH) {
        float s = lsum[t], q = lsq[t];
        if (s != 0.0f || q != 0.0f) {
            unsafeAtomicAdd(&gsum[t], s);
            unsafeAtomicAdd(&gsq[t], q);
        }
    }
}

// mean / rstd per graph (counts derived from last_idx of sorted batch)
__global__ void ln_fin_k(const float* __restrict__ gsum, const float* __restrict__ gsq,
                         const int* __restrict__ lastidx, float* __restrict__ mean,
                         float* __restrict__ rstd, int n) {
    int g = threadIdx.x;
    if (g >= NGRAPH) return;
    int last = lastidx[g];
    if (last < 0) last = 0; if (last >= n) last = n - 1;
    int prev = g ? lastidx[g - 1] : -1;
    if (prev < -1) prev = -1; if (prev >= n) prev = n - 1;
    float cnt = (float)(last - prev);
    if (cnt < 1.0f) cnt = 1.0f;
    float denom = cnt * (float)HDIM;
    float m = gsum[g] / denom;
    float v = gsq[g] / denom - m * m;
    if (v < 0.0f) v = 0.0f;
    mean[g] = m;
    rstd[g] = 1.0f / sqrtf(v + 1e-5f);
}

// h16 = tanh((h - mean)*rstd*w + b)  (fp32 in, fp16 out)
__global__ void ln_tanh_k(const float* __restrict__ h, const int* __restrict__ batch,
                          const float* __restrict__ mean, const float* __restrict__ rstd,
                          const float* __restrict__ w, const float* __restrict__ b,
                          __half* __restrict__ h16, int n) {
    long gid = (long)blockIdx.x * blockDim.x + threadIdx.x;
    long total = (long)n * 64;
    if (gid >= total) return;
    int i  = (int)(gid >> 6);
    int c  = (int)(gid & 63) * 4;
    int bg = batch[i];
    if (bg < 0) bg = 0; if (bg >= NGRAPH) bg = NGRAPH - 1;
    float m = mean[bg], r = rstd[bg];
    float4 v  = *(const float4*)(h + (size_t)i * HDIM + c);
    float4 w4 = *(const float4*)(w + c);
    float4 b4 = *(const float4*)(b + c);
    v.x = tanhf((v.x - m) * r * w4.x + b4.x);
    v.y = tanhf((v.y - m) * r * w4.y + b4.y);
    v.z = tanhf((v.z - m) * r * w4.z + b4.z);
    v.w = tanhf((v.w - m) * r * w4.w + b4.w);
    __half2 p0 = __float22half2_rn(make_float2(v.x, v.y));
    __half2 p1 = __float22half2_rn(make_float2(v.z, v.w));
    uint2 st; st.x = h22u(p0); st.y = h22u(p1);
    *(uint2*)(h16 + (size_t)i * HDIM + c) = st;
}

// gather the 64 last-node rows (fp16) of a layer output into xjk (fp32)
__global__ void extract_rows_k(const __half* __restrict__ x, const int* __restrict__ lastidx,
                               float* __restrict__ out, int n) {
    int g = blockIdx.x, c = threadIdx.x;
    int r = lastidx[g];
    if (r < 0) r = 0; if (r >= n) r = n - 1;
    out[(size_t)g * HDIM + c] = __half2float(x[(size_t)r * HDIM + c]);
}

// ---------------------------------------------------------------------------
// head: JK-cat [768] @ jk_w + jk_b -> tanh(fc1) -> fc2, one block per graph
__global__ __launch_bounds__(256) void final_mlp_k(
    const float* __restrict__ xjk,  // [3][64][256]
    const float* __restrict__ jk_w, const float* __restrict__ jk_b,
    const float* __restrict__ fc1_w, const float* __restrict__ fc1_b,
    const float* __restrict__ fc2_w, const float* __restrict__ fc2_b,
    float* __restrict__ out) {
    __shared__ float vec[3 * HDIM];
    __shared__ float h1[HDIM];
    __shared__ float h2[128];
    int g = blockIdx.x, t = threadIdx.x;
    vec[t]            = xjk[(size_t)0 * NGRAPH * HDIM + (size_t)g * HDIM + t];
    vec[HDIM + t]     = xjk[(size_t)1 * NGRAPH * HDIM + (size_t)g * HDIM + t];
    vec[2 * HDIM + t] = xjk[(size_t)2 * NGRAPH * HDIM + (size_t)g * HDIM + t];
    __syncthreads();
    float a = jk_b[t];
    for (int k = 0; k < 3 * HDIM; k++) a += vec[k] * jk_w[(size_t)k * HDIM + t];
    h1[t] = a;
    __syncthreads();
    if (t < 128) {
        float a2 = fc1_b[t];
        for (int k = 0; k < HDIM; k++) a2 += h1[k] * fc1_w[(size_t)k * 128 + t];
        h2[t] = tanhf(a2);
    }
    __syncthreads();
    if (t < 64) {
        float a3 = h2[t] * fc2_w[t] + h2[t + 64] * fc2_w[t + 64];
        for (int o = 32; o; o >>= 1) a3 += __shfl_down(a3, o);
        if (t == 0) out[g] = a3 + fc2_b[0];
    }
}

// ---------------------------------------------------------------------------
extern "C" void kernel_launch(void* const* d_in, const int* in_sizes, int n_in,
                              void* d_out, int out_size, void* d_ws, size_t ws_size,
                              hipStream_t stream) {
    const float* x    = (const float*)d_in[0];
    const float* W1   = (const float*)d_in[1];
    const float* b1   = (const float*)d_in[2];
    const float* ln1w = (const float*)d_in[3];
    const float* ln1b = (const float*)d_in[4];
    const float* W2   = (const float*)d_in[5];
    const float* b2   = (const float*)d_in[6];
    const float* ln2w = (const float*)d_in[7];
    const float* ln2b = (const float*)d_in[8];
    const float* W3   = (const float*)d_in[9];
    const float* b3   = (const float*)d_in[10];
    const float* ln3w = (const float*)d_in[11];
    const float* ln3b = (const float*)d_in[12];
    const float* jkw  = (const float*)d_in[13];
    const float* jkb  = (const float*)d_in[14];
    const float* fc1w = (const float*)d_in[15];
    const float* fc1b = (const float*)d_in[16];
    const float* fc2w = (const float*)d_in[17];
    const float* fc2b = (const float*)d_in[18];
    const int*  eidx  = (const int*)d_in[19];
    const int*  batch = (const int*)d_in[20];

    const int E = in_sizes[19] / 2;
    const int n = in_sizes[20];
    const int D = in_sizes[0] / n;  // 128

    const int* src = eidx;
    const int* dst = eidx + E;

    // workspace carve-up (~160 MB):
    char* base = (char*)d_ws;
    size_t o = 0;
    auto alloc = [&](size_t bytes) { void* p = base + o; o += (bytes + 255) & ~(size_t)255; return p; };
    __half* bufZ = (__half*)alloc((size_t)n * HDIM * 2);   // fp16 z
    float*  bufH = (float*)alloc((size_t)n * HDIM * 4);    // fp32 pre-LN h
    __half* hF   = (__half*)alloc((size_t)n * HDIM * 2);   // fp16 gather table (x16, then h16)
    __half* Wt   = (__half*)alloc((size_t)HDIM * HDIM * 2);// fp16 transposed weights
    int*   csr  = (int*)alloc((size_t)E * 4);
    int*   rs   = (int*)alloc((size_t)(n + 1) * 4);
    int*   cur  = (int*)alloc((size_t)n * 4);
    int*   degi = (int*)alloc((size_t)n * 4);
    float* dinv = (float*)alloc((size_t)n * 4);
    int*   part = (int*)alloc(1024 * 4);
    float* xjk  = (float*)alloc((size_t)3 * NGRAPH * HDIM * 4);
    int*   lidx = (int*)alloc(NGRAPH * 4);
    float* gsum = (float*)alloc(NGRAPH * 4);
    float* gsq  = (float*)alloc(NGRAPH * 4);
    float* mean = (float*)alloc(NGRAPH * 4);
    float* rstd = (float*)alloc(NGRAPH * 4);
    (void)ws_size;

    float* out = (float*)d_out;
    const int GB = (n + 31) / 32;                       // gemm blocks
    const int NB = (n + SCAN_CHUNK - 1) / SCAN_CHUNK;   // scan blocks (49)
    const int AB = 2048;                                // agg blocks (8192 waves)
    const int SB = 1024;                                // ln_stats blocks
    const int NPB = (n + SB - 1) / SB;                  // nodes per stats block (~98)

    // --- CSR build + degrees + last-node indices + x->fp16 (once per call) ---
    hipMemsetAsync(degi, 0, (size_t)n * 4, stream);
    hipMemsetAsync(lidx, 0, NGRAPH * 4, stream);
    deg_count_k<<<(E + 255) / 256, 256, 0, stream>>>(dst, degi, E, n);
    dinv_k<<<(n + 255) / 256, 256, 0, stream>>>(degi, dinv, n);
    last_idx_k<<<(n + 255) / 256, 256, 0, stream>>>(batch, lidx, n);
    scan1_k<<<NB, 256, 0, stream>>>(degi, part, n);
    scan2_k<<<1, 1024, 0, stream>>>(part, NB, rs, n);
    scan3_k<<<NB, 256, 0, stream>>>(degi, part, rs, cur, n);
    scatter_k<<<(E + 255) / 256, 256, 0, stream>>>(src, dst, cur, csr, E, n);
    long n4 = (long)n * D / 4;
    cvt_x_k<<<(int)((n4 + 255) / 256), 256, 0, stream>>>(x, hF, n4);  // hF holds x16 [n][128]

    // ---------------- layer 1 (K = 128) ----------------
    agg_csr_k<128><<<AB, 256, 0, stream>>>(rs, csr, hF, dinv, bufZ, n);
    cvt_w_k<<<128, 256, 0, stream>>>(W1, Wt, 128);
    gcn_gemm_k<128><<<GB, 256, 0, stream>>>(bufZ, Wt, b1, bufH, n);
    hipMemsetAsync(gsum, 0, 2 * NGRAPH * 4, stream);  // gsum+gsq contiguous
    ln_stats_k<<<SB, 256, 0, stream>>>(bufH, batch, gsum, gsq, n, NPB);
    ln_fin_k<<<1, 64, 0, stream>>>(gsum, gsq, lidx, mean, rstd, n);
    ln_tanh_k<<<(int)(((long)n * 64 + 255) / 256), 256, 0, stream>>>(bufH, batch, mean, rstd, ln1w, ln1b, hF, n);  // hF now h16 [n][256]
    extract_rows_k<<<NGRAPH, 256, 0, stream>>>(hF, lidx, xjk + 0 * NGRAPH * HDIM, n);

    // ---------------- layer 2 ----------------
    agg_csr_k<256><<<AB, 256, 0, stream>>>(rs, csr, hF, dinv, bufZ, n);
    cvt_w_k<<<256, 256, 0, stream>>>(W2, Wt, 256);
    gcn_gemm_k<256><<<GB, 256, 0, stream>>>(bufZ, Wt, b2, bufH, n);
    hipMemsetAsync(gsum, 0, 2 * NGRAPH * 4, stream);
    ln_stats_k<<<SB, 256, 0, stream>>>(bufH, batch, gsum, gsq, n, NPB);
    ln_fin_k<<<1, 64, 0, stream>>>(gsum, gsq, lidx, mean, rstd, n);
    ln_tanh_k<<<(int)(((long)n * 64 + 255) / 256), 256, 0, stream>>>(bufH, batch, mean, rstd, ln2w, ln2b, hF, n);
    extract_rows_k<<<NGRAPH, 256, 0, stream>>>(hF, lidx, xjk + 1 * NGRAPH * HDIM, n);

    // ---------------- layer 3 ----------------
    agg_csr_k<256><<<AB, 256, 0, stream>>>(rs, csr, hF, dinv, bufZ, n);
    cvt_w_k<<<256, 256, 0, stream>>>(W3, Wt, 256);
    gcn_gemm_k<256><<<GB, 256, 0, stream>>>(bufZ, Wt, b3, bufH, n);
    hipMemsetAsync(gsum, 0, 2 * NGRAPH * 4, stream);
    ln_stats_k<<<SB, 256, 0, stream>>>(bufH, batch, gsum, gsq, n, NPB);
    ln_fin_k<<<1, 64, 0, stream>>>(gsum, gsq, lidx, mean, rstd, n);
    ln_tanh_k<<<(int)(((long)n * 64 + 255) / 256), 256, 0, stream>>>(bufH, batch, mean, rstd, ln3w, ln3b, hF, n);
    extract_rows_k<<<NGRAPH, 256, 0, stream>>>(hF, lidx, xjk + 2 * NGRAPH * HDIM, n);

    // ---------------- head (64 nodes only) ----------------
    final_mlp_k<<<NGRAPH, 256, 0, stream>>>(xjk, jkw, jkb, fc1w, fc1b, fc2w, fc2b, out);
}

// Round 13
// 1078.684 us; speedup vs baseline: 3.9013x; 1.0516x over previous
//
#include <hip/hip_runtime.h>
#include <hip/hip_bf16.h>
#include <hip/hip_fp16.h>
#include <math.h>

// Problem constants: N=100000 nodes, E=1600000 edges, D=128, H=256, B=64.
// R5: 4208us. R6: 1981us (ln_stats LDS fix). R7: 1719us (gemm reg-tile).
// R10: 1420us (fp16 gather). R12: 1134us (MFMA f16 gemm).
// R13: agg_csr was L1-transaction-bound (64 lanes x 8B/row; 5.9TB/s effective
// gather rate identical to fp32 version -> not byte-bound). Fix: 16B/lane,
// 2 edges/wave (DIM=256) or 4 edges/wave (DIM=128) + shfl_xor merge.
#define HDIM 256
#define NGRAPH 64
#define SCAN_CHUNK 2048  // 256 threads x 8 elems

__device__ inline __half2 u2h2(unsigned u) { return *reinterpret_cast<__half2*>(&u); }
__device__ inline unsigned h22u(__half2 h) { return *reinterpret_cast<unsigned*>(&h); }

typedef _Float16 f16x8 __attribute__((ext_vector_type(8)));
typedef float    f32x4 __attribute__((ext_vector_type(4)));

// ---------------------------------------------------------------------------
// in-degree count (int atomics)
__global__ void deg_count_k(const int* __restrict__ dst, int* __restrict__ deg, int E, int n) {
    int i = blockIdx.x * blockDim.x + threadIdx.x;
    if (i < E) {
        int d = dst[i];
        if ((unsigned)d < (unsigned)n) atomicAdd(&deg[d], 1);
    }
}

// dinv[i] = 1/sqrt(in_deg[i] + 1)
__global__ void dinv_k(const int* __restrict__ deg, float* __restrict__ dinv, int n) {
    int i = blockIdx.x * blockDim.x + threadIdx.x;
    if (i < n) dinv[i] = 1.0f / sqrtf((float)deg[i] + 1.0f);
}

// last node index of each (sorted, consecutive) graph id
__global__ void last_idx_k(const int* __restrict__ batch, int* __restrict__ lastidx, int n) {
    int i = blockIdx.x * blockDim.x + threadIdx.x;
    if (i < n) {
        int b = batch[i];
        if ((i == n - 1 || batch[i + 1] != b) && b >= 0 && b < NGRAPH) lastidx[b] = i;
    }
}

// convert fp32 -> fp16 table (4 elems/thread)
__global__ void cvt_x_k(const float* __restrict__ x, __half* __restrict__ xh, long n4) {
    long i = (long)blockIdx.x * blockDim.x + threadIdx.x;
    if (i < n4) {
        float4 v = *(const float4*)(x + i * 4);
        __half2 p0 = __float22half2_rn(make_float2(v.x, v.y));
        __half2 p1 = __float22half2_rn(make_float2(v.z, v.w));
        uint2 st; st.x = h22u(p0); st.y = h22u(p1);
        *(uint2*)(xh + i * 4) = st;
    }
}

// W [K][256] fp32 -> Wt [256][K] fp16 (coalesced read, scattered 2B write; tiny)
__global__ void cvt_w_k(const float* __restrict__ W, __half* __restrict__ Wt, int K) {
    int idx = blockIdx.x * 256 + threadIdx.x;
    int k = idx >> 8, c = idx & 255;
    if (k < K) Wt[(size_t)c * K + k] = __float2half(W[(size_t)k * HDIM + c]);
}

// --------------------------- exclusive prefix scan -------------------------
__global__ __launch_bounds__(256) void scan1_k(const int* __restrict__ deg,
                                               int* __restrict__ partial, int n) {
    __shared__ int sm[256];
    int t = threadIdx.x;
    int base = blockIdx.x * SCAN_CHUNK + t * 8;
    int s = 0;
#pragma unroll
    for (int j = 0; j < 8; j++) { int idx = base + j; if (idx < n) s += deg[idx]; }
    sm[t] = s; __syncthreads();
    for (int o = 128; o; o >>= 1) { if (t < o) sm[t] += sm[t + o]; __syncthreads(); }
    if (t == 0) partial[blockIdx.x] = sm[0];
}

__global__ __launch_bounds__(1024) void scan2_k(int* __restrict__ partial, int nb,
                                                int* __restrict__ rs, int n) {
    __shared__ int sm[1024];
    int t = threadIdx.x;
    int v = (t < nb) ? partial[t] : 0;
    sm[t] = v; __syncthreads();
    for (int o = 1; o < 1024; o <<= 1) {
        int add = (t >= o) ? sm[t - o] : 0;
        __syncthreads();
        sm[t] += add;
        __syncthreads();
    }
    if (t < nb) partial[t] = sm[t] - v;  // exclusive block offset
    if (t == nb - 1) rs[n] = sm[t];      // total edge count
}

__global__ __launch_bounds__(256) void scan3_k(const int* __restrict__ deg,
                                               const int* __restrict__ partial,
                                               int* __restrict__ rs, int* __restrict__ cur, int n) {
    __shared__ int sm[256];
    int t = threadIdx.x;
    int base = blockIdx.x * SCAN_CHUNK + t * 8;
    int loc[8]; int s = 0;
#pragma unroll
    for (int j = 0; j < 8; j++) {
        int idx = base + j;
        loc[j] = (idx < n) ? deg[idx] : 0;
        s += loc[j];
    }
    sm[t] = s; __syncthreads();
    int v = s;
    for (int o = 1; o < 256; o <<= 1) {
        int add = (t >= o) ? sm[t - o] : 0;
        __syncthreads();
        sm[t] += add;
        __syncthreads();
    }
    int run = partial[blockIdx.x] + sm[t] - v;  // exclusive prefix for this thread
#pragma unroll
    for (int j = 0; j < 8; j++) {
        int idx = base + j;
        if (idx < n) { rs[idx] = run; cur[idx] = run; }
        run += loc[j];
    }
}

// scatter edges into CSR buckets (int atomics on cursors, ~E ops total)
__global__ void scatter_k(const int* __restrict__ src, const int* __restrict__ dst,
                          int* __restrict__ cur, int* __restrict__ csr, int E, int n) {
    int e = blockIdx.x * blockDim.x + threadIdx.x;
    if (e < E) {
        int d = dst[e], s = src[e];
        if ((unsigned)d < (unsigned)n && (unsigned)s < (unsigned)n) {
            int pos = atomicAdd(&cur[d], 1);
            csr[pos] = s;
        }
    }
}

// ---------------------------------------------------------------------------
// CSR aggregation, atomic-free. 16B/lane vector loads; NSUB edges processed
// concurrently by sub-waves (2 for DIM=256, 4 for DIM=128); shfl_xor merge.
// z[i] = dinv[i] * sum_{s in in(i)} dinv[s]*x[s]  +  dinv[i]^2 * x[i]
template <int DIM>
__global__ __launch_bounds__(256) void agg_csr_k(
    const int* __restrict__ rs, const int* __restrict__ csr,
    const __half* __restrict__ xin, const float* __restrict__ dinv,
    __half* __restrict__ z, int n) {
    constexpr int LPR  = DIM / 8;   // lanes per row (16B = 8 fp16 each): 32 or 16
    constexpr int NSUB = 64 / LPR;  // concurrent edges per wave: 2 or 4
    int wid  = (blockIdx.x * blockDim.x + threadIdx.x) >> 6;
    int lane = threadIdx.x & 63;
    int nw   = (gridDim.x * blockDim.x) >> 6;
    const int h  = lane / LPR;  // sub-wave id
    const int sl = lane % LPR;  // lane within row

    for (int i = wid; i < n; i += nw) {
        int j0 = rs[i], j1 = rs[i + 1];
        float acc[8];
#pragma unroll
        for (int v = 0; v < 8; v++) acc[v] = 0.0f;

        for (int jb = j0; jb < j1; jb += 64) {
            int m = j1 - jb; if (m > 64) m = 64;
            int   sj = (lane < m) ? csr[jb + lane] : 0;    // lane>=m: row 0, w=0
            float wj = (lane < m) ? dinv[sj] : 0.0f;
#pragma unroll 4
            for (int r = 0; r < m; r += NSUB) {
                int   s = __shfl(sj, r + h);   // r+h <= 63 always
                float w = __shfl(wj, r + h);
                const __half* xr = xin + (size_t)s * DIM + sl * 8;
                uint4 u = *(const uint4*)xr;   // 16B = 8 fp16
                float2 a0 = __half22float2(u2h2(u.x));
                float2 a1 = __half22float2(u2h2(u.y));
                float2 a2 = __half22float2(u2h2(u.z));
                float2 a3 = __half22float2(u2h2(u.w));
                acc[0] += a0.x * w; acc[1] += a0.y * w;
                acc[2] += a1.x * w; acc[3] += a1.y * w;
                acc[4] += a2.x * w; acc[5] += a2.y * w;
                acc[6] += a3.x * w; acc[7] += a3.y * w;
            }
        }

        // merge sub-wave partial sums (same columns, different edge subsets)
        if (NSUB == 4) {
#pragma unroll
            for (int v = 0; v < 8; v++) acc[v] += __shfl_xor(acc[v], 16);
        }
#pragma unroll
        for (int v = 0; v < 8; v++) acc[v] += __shfl_xor(acc[v], 32);

        if (h == 0) {
            float di  = dinv[i];
            float di2 = di * di;
            const __half* xr = xin + (size_t)i * DIM + sl * 8;
            uint4 u = *(const uint4*)xr;
            float2 a0 = __half22float2(u2h2(u.x));
            float2 a1 = __half22float2(u2h2(u.y));
            float2 a2 = __half22float2(u2h2(u.z));
            float2 a3 = __half22float2(u2h2(u.w));
            float o0 = di * acc[0] + di2 * a0.x, o1 = di * acc[1] + di2 * a0.y;
            float o2 = di * acc[2] + di2 * a1.x, o3 = di * acc[3] + di2 * a1.y;
            float o4 = di * acc[4] + di2 * a2.x, o5 = di * acc[5] + di2 * a2.y;
            float o6 = di * acc[6] + di2 * a3.x, o7 = di * acc[7] + di2 * a3.y;
            uint4 st;
            st.x = h22u(__float22half2_rn(make_float2(o0, o1)));
            st.y = h22u(__float22half2_rn(make_float2(o2, o3)));
            st.z = h22u(__float22half2_rn(make_float2(o4, o5)));
            st.w = h22u(__float22half2_rn(make_float2(o6, o7)));
            *(uint4*)(z + (size_t)i * DIM + sl * 8) = st;
        }
    }
}

// ---------------------------------------------------------------------------
// MFMA GEMM: h = z @ W + bias, fp16 inputs, fp32 accumulate/output. (R12)
template <int K>
__global__ __launch_bounds__(256) void gcn_gemm_k(
    const __half* __restrict__ z, const __half* __restrict__ Wt,
    const float* __restrict__ bias, float* __restrict__ hout, int n) {
    const int t   = threadIdx.x;
    const int wv  = t >> 6;
    const int l   = t & 63;
    const int l15 = l & 15;
    const int lhi = l >> 4;  // 0..3
    const int r0  = blockIdx.x * 32;
    const int c0  = wv * 64;

    f32x4 acc[2][4];
#pragma unroll
    for (int cg = 0; cg < 4; cg++) {
        float bv = bias[c0 + cg * 16 + l15];
        f32x4 b4 = {bv, bv, bv, bv};
        acc[0][cg] = b4;
        acc[1][cg] = b4;
    }

    int ra = r0 + l15;      if (ra >= n) ra = n - 1;  // clamped (stores guarded)
    int rb = r0 + 16 + l15; if (rb >= n) rb = n - 1;
    const __half* za = z + (size_t)ra * K + lhi * 8;
    const __half* zb = z + (size_t)rb * K + lhi * 8;
    const __half* wp0 = Wt + (size_t)(c0 + 0 * 16 + l15) * K + lhi * 8;
    const __half* wp1 = Wt + (size_t)(c0 + 1 * 16 + l15) * K + lhi * 8;
    const __half* wp2 = Wt + (size_t)(c0 + 2 * 16 + l15) * K + lhi * 8;
    const __half* wp3 = Wt + (size_t)(c0 + 3 * 16 + l15) * K + lhi * 8;

#pragma unroll
    for (int ks = 0; ks < K; ks += 32) {
        f16x8 a0 = *(const f16x8*)(za + ks);
        f16x8 a1 = *(const f16x8*)(zb + ks);
        f16x8 b0 = *(const f16x8*)(wp0 + ks);
        f16x8 b1 = *(const f16x8*)(wp1 + ks);
        f16x8 b2 = *(const f16x8*)(wp2 + ks);
        f16x8 b3 = *(const f16x8*)(wp3 + ks);
        acc[0][0] = __builtin_amdgcn_mfma_f32_16x16x32_f16(a0, b0, acc[0][0], 0, 0, 0);
        acc[1][0] = __builtin_amdgcn_mfma_f32_16x16x32_f16(a1, b0, acc[1][0], 0, 0, 0);
        acc[0][1] = __builtin_amdgcn_mfma_f32_16x16x32_f16(a0, b1, acc[0][1], 0, 0, 0);
        acc[1][1] = __builtin_amdgcn_mfma_f32_16x16x32_f16(a1, b1, acc[1][1], 0, 0, 0);
        acc[0][2] = __builtin_amdgcn_mfma_f32_16x16x32_f16(a0, b2, acc[0][2], 0, 0, 0);
        acc[1][2] = __builtin_amdgcn_mfma_f32_16x16x32_f16(a1, b2, acc[1][2], 0, 0, 0);
        acc[0][3] = __builtin_amdgcn_mfma_f32_16x16x32_f16(a0, b3, acc[0][3], 0, 0, 0);
        acc[1][3] = __builtin_amdgcn_mfma_f32_16x16x32_f16(a1, b3, acc[1][3], 0, 0, 0);
    }

#pragma unroll
    for (int rg = 0; rg < 2; rg++) {
#pragma unroll
        for (int i = 0; i < 4; i++) {
            int r = r0 + rg * 16 + lhi * 4 + i;
            if (r < n) {
                float* hp = hout + (size_t)r * HDIM + c0 + l15;
#pragma unroll
                for (int cg = 0; cg < 4; cg++)
                    hp[cg * 16] = acc[rg][cg][i];
            }
        }
    }
}

// ---------------------------------------------------------------------------
// per-graph sum/sumsq, hierarchical: contiguous node slab per block,
// LDS per-graph accumulators, few global atomics per block. (R6 fix)
__global__ __launch_bounds__(256) void ln_stats_k(
    const float* __restrict__ h, const int* __restrict__ batch,
    float* __restrict__ gsum, float* __restrict__ gsq, int n, int npb) {
    __shared__ float lsum[NGRAPH], lsq[NGRAPH];
    int t = threadIdx.x;
    if (t < NGRAPH) { lsum[t] = 0.0f; lsq[t] = 0.0f; }
    __syncthreads();
    int wv = t >> 6, lane = t & 63;
    int i0 = blockIdx.x * npb;
    int i1 = i0 + npb; if (i1 > n) i1 = n;
    for (int i = i0 + wv; i < i1; i += 4) {
        float4 v = *(const float4*)(h + (size_t)i * HDIM + lane * 4);
        float s = v.x + v.y + v.z + v.w;
        float q = v.x * v.x + v.y * v.y + v.z * v.z + v.w * v.w;
        for (int o = 32; o; o >>= 1) {
            s += __shfl_down(s, o);
            q += __shfl_down(q, o);
        }
        if (lane == 0) {
            int b = batch[i];
            if (b < 0) b = 0; if (b >= NGRAPH) b = NGRAPH - 1;
            atomicAdd(&lsum[b], s);  // LDS atomic
            atomicAdd(&lsq[b], q);
        }
    }
    __syncthreads();
    if (t < NGRAPH) {
        float s = lsum[t], q = lsq[t];
        if (s != 0.0f || q != 0.0f) {
            unsafeAtomicAdd(&gsum[t], s);
            unsafeAtomicAdd(&gsq[t], q);
        }
    }
}

// mean / rstd per graph (counts derived from last_idx of sorted batch)
__global__ void ln_fin_k(const float* __restrict__ gsum, const float* __restrict__ gsq,
                         const int* __restrict__ lastidx, float* __restrict__ mean,
                         float* __restrict__ rstd, int n) {
    int g = threadIdx.x;
    if (g >= NGRAPH) return;
    int last = lastidx[g];
    if (last < 0) last = 0; if (last >= n) last = n - 1;
    int prev = g ? lastidx[g - 1] : -1;
    if (prev < -1) prev = -1; if (prev >= n) prev = n - 1;
    float cnt = (float)(last - prev);
    if (cnt < 1.0f) cnt = 1.0f;
    float denom = cnt * (float)HDIM;
    float m = gsum[g] / denom;
    float v = gsq[g] / denom - m * m;
    if (v < 0.0f) v = 0.0f;
    mean[g] = m;
    rstd[g] = 1.0f / sqrtf(v + 1e-5f);
}

// h16 = tanh((h - mean)*rstd*w + b)  (fp32 in, fp16 out)
__global__ void ln_tanh_k(const float* __restrict__ h, const int* __restrict__ batch,
                          const float* __restrict__ mean, const float* __restrict__ rstd,
                          const float* __restrict__ w, const float* __restrict__ b,
                          __half* __restrict__ h16, int n) {
    long gid = (long)blockIdx.x * blockDim.x + threadIdx.x;
    long total = (long)n * 64;
    if (gid >= total) return;
    int i  = (int)(gid >> 6);
    int c  = (int)(gid & 63) * 4;
    int bg = batch[i];
    if (bg < 0) bg = 0; if (bg >= NGRAPH) bg = NGRAPH - 1;
    float m = mean[bg], r = rstd[bg];
    float4 v  = *(const float4*)(h + (size_t)i * HDIM + c);
    float4 w4 = *(const float4*)(w + c);
    float4 b4 = *(const float4*)(b + c);
    v.x = tanhf((v.x - m) * r * w4.x + b4.x);
    v.y = tanhf((v.y - m) * r * w4.y + b4.y);
    v.z = tanhf((v.z - m) * r * w4.z + b4.z);
    v.w = tanhf((v.w - m) * r * w4.w + b4.w);
    __half2 p0 = __float22half2_rn(make_float2(v.x, v.y));
    __half2 p1 = __float22half2_rn(make_float2(v.z, v.w));
    uint2 st; st.x = h22u(p0); st.y = h22u(p1);
    *(uint2*)(h16 + (size_t)i * HDIM + c) = st;
}

// gather the 64 last-node rows (fp16) of a layer output into xjk (fp32)
__global__ void extract_rows_k(const __half* __restrict__ x, const int* __restrict__ lastidx,
                               float* __restrict__ out, int n) {
    int g = blockIdx.x, c = threadIdx.x;
    int r = lastidx[g];
    if (r < 0) r = 0; if (r >= n) r = n - 1;
    out[(size_t)g * HDIM + c] = __half2float(x[(size_t)r * HDIM + c]);
}

// ---------------------------------------------------------------------------
// head: JK-cat [768] @ jk_w + jk_b -> tanh(fc1) -> fc2, one block per graph
__global__ __launch_bounds__(256) void final_mlp_k(
    const float* __restrict__ xjk,  // [3][64][256]
    const float* __restrict__ jk_w, const float* __restrict__ jk_b,
    const float* __restrict__ fc1_w, const float* __restrict__ fc1_b,
    const float* __restrict__ fc2_w, const float* __restrict__ fc2_b,
    float* __restrict__ out) {
    __shared__ float vec[3 * HDIM];
    __shared__ float h1[HDIM];
    __shared__ float h2[128];
    int g = blockIdx.x, t = threadIdx.x;
    vec[t]            = xjk[(size_t)0 * NGRAPH * HDIM + (size_t)g * HDIM + t];
    vec[HDIM + t]     = xjk[(size_t)1 * NGRAPH * HDIM + (size_t)g * HDIM + t];
    vec[2 * HDIM + t] = xjk[(size_t)2 * NGRAPH * HDIM + (size_t)g * HDIM + t];
    __syncthreads();
    float a = jk_b[t];
    for (int k = 0; k < 3 * HDIM; k++) a += vec[k] * jk_w[(size_t)k * HDIM + t];
    h1[t] = a;
    __syncthreads();
    if (t < 128) {
        float a2 = fc1_b[t];
        for (int k = 0; k < HDIM; k++) a2 += h1[k] * fc1_w[(size_t)k * 128 + t];
        h2[t] = tanhf(a2);
    }
    __syncthreads();
    if (t < 64) {
        float a3 = h2[t] * fc2_w[t] + h2[t + 64] * fc2_w[t + 64];
        for (int o = 32; o; o >>= 1) a3 += __shfl_down(a3, o);
        if (t == 0) out[g] = a3 + fc2_b[0];
    }
}

// ---------------------------------------------------------------------------
extern "C" void kernel_launch(void* const* d_in, const int* in_sizes, int n_in,
                              void* d_out, int out_size, void* d_ws, size_t ws_size,
                              hipStream_t stream) {
    const float* x    = (const float*)d_in[0];
    const float* W1   = (const float*)d_in[1];
    const float* b1   = (const float*)d_in[2];
    const float* ln1w = (const float*)d_in[3];
    const float* ln1b = (const float*)d_in[4];
    const float* W2   = (const float*)d_in[5];
    const float* b2   = (const float*)d_in[6];
    const float* ln2w = (const float*)d_in[7];
    const float* ln2b = (const float*)d_in[8];
    const float* W3   = (const float*)d_in[9];
    const float* b3   = (const float*)d_in[10];
    const float* ln3w = (const float*)d_in[11];
    const float* ln3b = (const float*)d_in[12];
    const float* jkw  = (const float*)d_in[13];
    const float* jkb  = (const float*)d_in[14];
    const float* fc1w = (const float*)d_in[15];
    const float* fc1b = (const float*)d_in[16];
    const float* fc2w = (const float*)d_in[17];
    const float* fc2b = (const float*)d_in[18];
    const int*  eidx  = (const int*)d_in[19];
    const int*  batch = (const int*)d_in[20];

    const int E = in_sizes[19] / 2;
    const int n = in_sizes[20];
    const int D = in_sizes[0] / n;  // 128

    const int* src = eidx;
    const int* dst = eidx + E;

    // workspace carve-up (~160 MB):
    char* base = (char*)d_ws;
    size_t o = 0;
    auto alloc = [&](size_t bytes) { void* p = base + o; o += (bytes + 255) & ~(size_t)255; return p; };
    __half* bufZ = (__half*)alloc((size_t)n * HDIM * 2);   // fp16 z
    float*  bufH = (float*)alloc((size_t)n * HDIM * 4);    // fp32 pre-LN h
    __half* hF   = (__half*)alloc((size_t)n * HDIM * 2);   // fp16 gather table (x16, then h16)
    __half* Wt   = (__half*)alloc((size_t)HDIM * HDIM * 2);// fp16 transposed weights
    int*   csr  = (int*)alloc((size_t)E * 4);
    int*   rs   = (int*)alloc((size_t)(n + 1) * 4);
    int*   cur  = (int*)alloc((size_t)n * 4);
    int*   degi = (int*)alloc((size_t)n * 4);
    float* dinv = (float*)alloc((size_t)n * 4);
    int*   part = (int*)alloc(1024 * 4);
    float* xjk  = (float*)alloc((size_t)3 * NGRAPH * HDIM * 4);
    int*   lidx = (int*)alloc(NGRAPH * 4);
    float* gsum = (float*)alloc(NGRAPH * 4);
    float* gsq  = (float*)alloc(NGRAPH * 4);
    float* mean = (float*)alloc(NGRAPH * 4);
    float* rstd = (float*)alloc(NGRAPH * 4);
    (void)ws_size;

    float* out = (float*)d_out;
    const int GB = (n + 31) / 32;                       // gemm blocks
    const int NB = (n + SCAN_CHUNK - 1) / SCAN_CHUNK;   // scan blocks (49)
    const int AB = 2048;                                // agg blocks (8192 waves)
    const int SB = 1024;                                // ln_stats blocks
    const int NPB = (n + SB - 1) / SB;                  // nodes per stats block (~98)

    // --- CSR build + degrees + last-node indices + x->fp16 (once per call) ---
    hipMemsetAsync(degi, 0, (size_t)n * 4, stream);
    hipMemsetAsync(lidx, 0, NGRAPH * 4, stream);
    deg_count_k<<<(E + 255) / 256, 256, 0, stream>>>(dst, degi, E, n);
    dinv_k<<<(n + 255) / 256, 256, 0, stream>>>(degi, dinv, n);
    last_idx_k<<<(n + 255) / 256, 256, 0, stream>>>(batch, lidx, n);
    scan1_k<<<NB, 256, 0, stream>>>(degi, part, n);
    scan2_k<<<1, 1024, 0, stream>>>(part, NB, rs, n);
    scan3_k<<<NB, 256, 0, stream>>>(degi, part, rs, cur, n);
    scatter_k<<<(E + 255) / 256, 256, 0, stream>>>(src, dst, cur, csr, E, n);
    long n4 = (long)n * D / 4;
    cvt_x_k<<<(int)((n4 + 255) / 256), 256, 0, stream>>>(x, hF, n4);  // hF holds x16 [n][128]

    // ---------------- layer 1 (K = 128) ----------------
    agg_csr_k<128><<<AB, 256, 0, stream>>>(rs, csr, hF, dinv, bufZ, n);
    cvt_w_k<<<128, 256, 0, stream>>>(W1, Wt, 128);
    gcn_gemm_k<128><<<GB, 256, 0, stream>>>(bufZ, Wt, b1, bufH, n);
    hipMemsetAsync(gsum, 0, 2 * NGRAPH * 4, stream);  // gsum+gsq contiguous
    ln_stats_k<<<SB, 256, 0, stream>>>(bufH, batch, gsum, gsq, n, NPB);
    ln_fin_k<<<1, 64, 0, stream>>>(gsum, gsq, lidx, mean, rstd, n);
    ln_tanh_k<<<(int)(((long)n * 64 + 255) / 256), 256, 0, stream>>>(bufH, batch, mean, rstd, ln1w, ln1b, hF, n);  // hF now h16 [n][256]
    extract_rows_k<<<NGRAPH, 256, 0, stream>>>(hF, lidx, xjk + 0 * NGRAPH * HDIM, n);

    // ---------------- layer 2 ----------------
    agg_csr_k<256><<<AB, 256, 0, stream>>>(rs, csr, hF, dinv, bufZ, n);
    cvt_w_k<<<256, 256, 0, stream>>>(W2, Wt, 256);
    gcn_gemm_k<256><<<GB, 256, 0, stream>>>(bufZ, Wt, b2, bufH, n);
    hipMemsetAsync(gsum, 0, 2 * NGRAPH * 4, stream);
    ln_stats_k<<<SB, 256, 0, stream>>>(bufH, batch, gsum, gsq, n, NPB);
    ln_fin_k<<<1, 64, 0, stream>>>(gsum, gsq, lidx, mean, rstd, n);
    ln_tanh_k<<<(int)(((long)n * 64 + 255) / 256), 256, 0, stream>>>(bufH, batch, mean, rstd, ln2w, ln2b, hF, n);
    extract_rows_k<<<NGRAPH, 256, 0, stream>>>(hF, lidx, xjk + 1 * NGRAPH * HDIM, n);

    // ---------------- layer 3 ----------------
    agg_csr_k<256><<<AB, 256, 0, stream>>>(rs, csr, hF, dinv, bufZ, n);
    cvt_w_k<<<256, 256, 0, stream>>>(W3, Wt, 256);
    gcn_gemm_k<256><<<GB, 256, 0, stream>>>(bufZ, Wt, b3, bufH, n);
    hipMemsetAsync(gsum, 0, 2 * NGRAPH * 4, stream);
    ln_stats_k<<<SB, 256, 0, stream>>>(bufH, batch, gsum, gsq, n, NPB);
    ln_fin_k<<<1, 64, 0, stream>>>(gsum, gsq, lidx, mean, rstd, n);
    ln_tanh_k<<<(int)(((long)n * 64 + 255) / 256), 256, 0, stream>>>(bufH, batch, mean, rstd, ln3w, ln3b, hF, n);
    extract_rows_k<<<NGRAPH, 256, 0, stream>>>(hF, lidx, xjk + 2 * NGRAPH * HDIM, n);

    // ---------------- head (64 nodes only) ----------------
    final_mlp_k<<<NGRAPH, 256, 0, stream>>>(xjk, jkw, jkb, fc1w, fc1b, fc2w, fc2b, out);
}